// Round 1
// 443.619 us; speedup vs baseline: 1.0626x; 1.0626x over previous
//
#include <hip/hip_runtime.h>
#include <hip/hip_bf16.h>
#include <math.h>

// Problem constants
#define BB 2
#define SS 2048
#define DDIM 1024
#define NHEAD 16
#define NSTR 8
#define SDIMC 128
#define NCH 16      // chunks for delta scan
#define CLEN 128    // chunk length
#define EPSV 1e-6f

using bf16 = __hip_bfloat16;
typedef __attribute__((ext_vector_type(8))) __bf16 bf8;
typedef __attribute__((ext_vector_type(4))) __bf16 bf4v;
typedef __attribute__((ext_vector_type(4))) float f4;

__device__ __forceinline__ bf16 f2b(float v) { return __float2bfloat16(v); }
__device__ __forceinline__ bf8 ld8(const bf16* p) { return *(const bf8*)p; }
__device__ __forceinline__ f4 MFMA(bf8 a, bf8 b, f4 c) {
  return __builtin_amdgcn_mfma_f32_16x16x32_bf16(a, b, c, 0, 0, 0);
}
__device__ __forceinline__ float sigm(float x) { return 1.0f / (1.0f + expf(-x)); }
__device__ __forceinline__ float fexp2(float x) { return __builtin_amdgcn_exp2f(x); }

// fast gelu (exact-erf form) via Abramowitz-Stegun 7.1.26: |erf err| <= 1.5e-7,
// far below bf16 store rounding. hw rcp + hw exp2 instead of libm erff.
__device__ __forceinline__ float gelu_f(float v) {
  float x = v * 0.70710678118654752f;
  float ax = fabsf(x);
  float t = __builtin_amdgcn_rcpf(1.0f + 0.3275911f * ax);
  float p = ((((1.061405429f * t - 1.453152027f) * t + 1.421413741f) * t
              - 0.284496736f) * t + 0.254829592f) * t;
  float e = 1.0f - p * fexp2(-ax * ax * 1.4426950408889634f);
  e = copysignf(e, x);
  return 0.5f * v * (1.0f + e);
}

// async global->LDS 16B copy (m97 pattern; LDS dest must be uniform + lane*16)
__device__ __forceinline__ void glds16(bf16* l, const bf16* g) {
  __builtin_amdgcn_global_load_lds(
      (const __attribute__((address_space(1))) unsigned int*)g,
      (__attribute__((address_space(3))) unsigned int*)l, 16, 0, 0);
}

// ---------------- f32 -> bf16 weight conversion (all 4 weights, one launch) --
__global__ __launch_bounds__(256) void cvt_all(const float* __restrict__ ipw,
                                               const float* __restrict__ ow,
                                               const float* __restrict__ w1,
                                               const float* __restrict__ w2,
                                               bf16* __restrict__ WIPW,
                                               bf16* __restrict__ WOW,
                                               bf16* __restrict__ W1B,
                                               bf16* __restrict__ W2B) {
  const int S1 = 3 * DDIM * DDIM, S2 = S1 + DDIM * DDIM,
            S3 = S2 + 4 * DDIM * DDIM;
  int i4 = (blockIdx.x * 256 + threadIdx.x) * 4;   // grid covers 12.58M elems
  const float* src;
  bf16* dst;
  int off;
  if (i4 < S1)      { src = ipw; dst = WIPW; off = i4; }
  else if (i4 < S2) { src = ow;  dst = WOW;  off = i4 - S1; }
  else if (i4 < S3) { src = w1;  dst = W1B;  off = i4 - S2; }
  else              { src = w2;  dst = W2B;  off = i4 - S3; }
  float4 v = *(const float4*)(src + off);
  bf4v o;
  o[0] = (__bf16)v.x; o[1] = (__bf16)v.y; o[2] = (__bf16)v.z; o[3] = (__bf16)v.w;
  *(bf4v*)(dst + off) = o;                         // one 8B store, fully packed
}

// ---------------- Delta operator: 3-pass chunked affine scan ----------------
__global__ __launch_bounds__(256) void delta_passA(const float* __restrict__ x,
                                                   const float* __restrict__ decay,
                                                   float* __restrict__ SA) {
  int idx = blockIdx.x * 256 + threadIdx.x;      // [b][c][d]
  int d = idx % DDIM;
  int c = (idx / DDIM) % NCH;
  int b = idx / (DDIM * NCH);
  float beta = sigm(decay[d]);
  float omb = 1.0f - beta;
  const float* xp = x + ((size_t)(b * SS + c * CLEN)) * DDIM + d;
  float s = 0.0f;
  for (int j = 0; j < CLEN; j++) {
    float xv = xp[(size_t)j * DDIM];
    s = beta * s + omb * xv;
  }
  SA[idx] = s;
}

__global__ __launch_bounds__(256) void delta_passB(const float* __restrict__ SA,
                                                   const float* __restrict__ decay,
                                                   float* __restrict__ SIN) {
  int idx = blockIdx.x * 256 + threadIdx.x;      // [b][d]
  int d = idx % DDIM;
  int b = idx / DDIM;
  float beta = sigm(decay[d]);
  float p = beta;
  for (int i = 0; i < 7; i++) p *= p;            // beta^128
  float s = 0.0f;
  for (int c = 0; c < NCH; c++) {
    SIN[(b * NCH + c) * DDIM + d] = s;
    s = p * s + SA[(b * NCH + c) * DDIM + d];
  }
}

__global__ __launch_bounds__(256) void delta_passC(const float* __restrict__ x,
                                                   const float* __restrict__ decay,
                                                   const float* __restrict__ SIN,
                                                   float* __restrict__ XD,
                                                   float* __restrict__ SA) {
  int idx = blockIdx.x * 256 + threadIdx.x;      // [b][c][d]
  int d = idx % DDIM;
  int c = (idx / DDIM) % NCH;
  int b = idx / (DDIM * NCH);
  float beta = sigm(decay[d]);
  float omb = 1.0f - beta;
  const float* xp = x + ((size_t)(b * SS + c * CLEN)) * DDIM + d;
  float* xdp = XD + ((size_t)(b * SS + c * CLEN)) * DDIM + d;
  float s = SIN[idx];
  float sum = 0.0f;
  for (int j = 0; j < CLEN; j++) {
    float xv = xp[(size_t)j * DDIM];
    float o = xv - s;
    xdp[(size_t)j * DDIM] = o;
    sum += o;
    s = beta * s + omb * xv;
  }
  SA[idx] = sum;
}

// ---------------- gates (g_res) + sinkhorn ----------------
__global__ __launch_bounds__(1024) void gates_sinkhorn(const float* __restrict__ SA,
                                                       const float* __restrict__ gw,
                                                       const float* __restrict__ gb,
                                                       const float* __restrict__ phi,
                                                       float* __restrict__ gres,
                                                       float* __restrict__ hres) {
  int tid = threadIdx.x;
  int wave = tid >> 6, lane = tid & 63;
  int b = wave >> 3, j = wave & 7;               // 16 waves: (b, gate j)
  float acc = 0.0f;
  for (int d = lane; d < DDIM; d += 64) {
    float xs = 0.0f;
    for (int c = 0; c < NCH; c++) xs += SA[(b * NCH + c) * DDIM + d];
    xs *= (1.0f / (float)SS);
    acc += xs * gw[(2 * NSTR + j) * DDIM + d];
  }
  for (int off = 32; off > 0; off >>= 1) acc += __shfl_down(acc, off);
  if (lane == 0) gres[b * NSTR + j] = sigm(acc + gb[2 * NSTR + j]);
  __syncthreads();
  if (tid == 0) {
    float Km[8][8];
    for (int i = 0; i < 8; i++)
      for (int jj = 0; jj < 8; jj++) Km[i][jj] = expf(phi[i * 8 + jj]);
    for (int it = 0; it < 15; it++) {
      for (int i = 0; i < 8; i++) {
        float rs = 0.0f;
        for (int jj = 0; jj < 8; jj++) rs += Km[i][jj];
        float inv = 1.0f / rs;
        for (int jj = 0; jj < 8; jj++) Km[i][jj] *= inv;
      }
      for (int jj = 0; jj < 8; jj++) {
        float cs = 0.0f;
        for (int i = 0; i < 8; i++) cs += Km[i][jj];
        float inv = 1.0f / cs;
        for (int i = 0; i < 8; i++) Km[i][jj] *= inv;
      }
    }
    for (int i = 0; i < 8; i++)
      for (int jj = 0; jj < 8; jj++) hres[i * 8 + jj] = Km[i][jj];
  }
}

// ---------------- RMSNorm (f32 in -> bf16 out) ----------------
__global__ __launch_bounds__(256) void rmsnorm_k(const float* __restrict__ in,
                                                 const float* __restrict__ w,
                                                 bf16* __restrict__ out) {
  int row = blockIdx.x;
  const float* r = in + (size_t)row * DDIM;
  int tid = threadIdx.x;
  float ss = 0.0f;
  for (int i = tid; i < DDIM; i += 256) {
    float v = r[i];
    ss += v * v;
  }
  for (int off = 32; off > 0; off >>= 1) ss += __shfl_down(ss, off);
  __shared__ float red[4];
  if ((tid & 63) == 0) red[tid >> 6] = ss;
  __syncthreads();
  float tot = red[0] + red[1] + red[2] + red[3];
  float sc = rsqrtf(tot / (float)DDIM + EPSV);
  bf16* o = out + (size_t)row * DDIM;
  for (int i = tid; i < DDIM; i += 256) o[i] = f2b(r[i] * sc * w[i]);
}

// ------- MFMA GEMM, 128x128 tile, BK=32, DOUBLE-BUFFERED single-barrier loop.
// T3-minimal recipe: issue next tile's global_load_lds BEFORE ds_read+MFMA of
// current tile; one __syncthreads (vmcnt(0)+lgkmcnt(0)+barrier) per K-step.
// ODT: 0=f32 out, 1=bf16 out.  EPI: 0=none, 1=gelu(exact erf), 2=add residual
template <int ODT, int EPI>
__global__ __launch_bounds__(256) void gemm_lds(const bf16* __restrict__ A,
                                                const bf16* __restrict__ W,
                                                const float* __restrict__ bias,
                                                const float* __restrict__ res,
                                                void* __restrict__ outp,
                                                int M, int N, int K) {
  __shared__ bf16 As[2][128 * 32];
  __shared__ bf16 Bs[2][128 * 32];
  int tid = threadIdx.x;
  int lane = tid & 63, wv = tid >> 6;
  int ml = lane & 15, quad = lane >> 4;
  int wr = wv >> 1, wc = wv & 1;
  int m0 = blockIdx.x * 128, n0 = blockIdx.y * 128;
  // per-thread staging addresses (2 chunks each of A,B)
  const bf16* ga[2];
  const bf16* gb[2];
  int lofs[2];
#pragma unroll
  for (int it = 0; it < 2; it++) {
    int c = it * 256 + tid;             // 512 16B-chunks per tile
    int row = c >> 2, kc = (c & 3) * 8;
    ga[it] = A + (size_t)(m0 + row) * K + kc;
    gb[it] = W + (size_t)(n0 + row) * K + kc;
    lofs[it] = c * 8;
  }
  // prologue: stage tile 0 into buffer 0
#pragma unroll
  for (int it = 0; it < 2; it++) {
    glds16(&As[0][lofs[it]], ga[it]);
    glds16(&Bs[0][lofs[it]], gb[it]);
  }
  f4 acc[4][4] = {};
  int nk = K >> 5;
  int cur = 0;
  __syncthreads();
  for (int t = 0; t < nk; t++) {
    if (t + 1 < nk) {                    // prefetch tile t+1 into other buffer
      int ko = (t + 1) * 32;
#pragma unroll
      for (int it = 0; it < 2; it++) {
        glds16(&As[cur ^ 1][lofs[it]], ga[it] + ko);
        glds16(&Bs[cur ^ 1][lofs[it]], gb[it] + ko);
      }
    }
    bf8 af[4], bfr[4];
#pragma unroll
    for (int mi = 0; mi < 4; mi++)
      af[mi] = ld8(&As[cur][(wr * 64 + mi * 16 + ml) * 32 + quad * 8]);
#pragma unroll
    for (int ni = 0; ni < 4; ni++)
      bfr[ni] = ld8(&Bs[cur][(wc * 64 + ni * 16 + ml) * 32 + quad * 8]);
#pragma unroll
    for (int mi = 0; mi < 4; mi++)
#pragma unroll
      for (int ni = 0; ni < 4; ni++)
        acc[mi][ni] = MFMA(af[mi], bfr[ni], acc[mi][ni]);
    __syncthreads();                     // vmcnt(0)+lgkmcnt(0)+barrier
    cur ^= 1;
  }
#pragma unroll
  for (int mi = 0; mi < 4; mi++)
#pragma unroll
    for (int ni = 0; ni < 4; ni++)
#pragma unroll
      for (int r = 0; r < 4; r++) {
        int row = m0 + wr * 64 + mi * 16 + quad * 4 + r;
        int col = n0 + wc * 64 + ni * 16 + ml;
        size_t idx = (size_t)row * N + col;
        float v = acc[mi][ni][r] + bias[col];
        if (EPI == 1) v = gelu_f(v);
        if (EPI == 2) v += res[idx];
        if (ODT == 1) ((bf16*)outp)[idx] = f2b(v);
        else ((float*)outp)[idx] = v;
      }
}

// ------- ffn2 split-K=2, ONE launch, grid (32,8,2): z picks K-slice+buffer ---
// same double-buffered single-barrier structure
__global__ __launch_bounds__(256) void gemm_part2(const bf16* __restrict__ A,
                                                  const bf16* __restrict__ W,
                                                  float* __restrict__ P0,
                                                  float* __restrict__ P1,
                                                  int M, int N, int KS, int LDK) {
  __shared__ bf16 As[2][128 * 32];
  __shared__ bf16 Bs[2][128 * 32];
  int tid = threadIdx.x;
  int lane = tid & 63, wv = tid >> 6;
  int ml = lane & 15, quad = lane >> 4;
  int wr = wv >> 1, wc = wv & 1;
  int m0 = blockIdx.x * 128, n0 = blockIdx.y * 128;
  const bf16* Ab = A + blockIdx.z * KS;
  const bf16* Wb = W + blockIdx.z * KS;
  float* P = blockIdx.z ? P1 : P0;
  const bf16* ga[2];
  const bf16* gb[2];
  int lofs[2];
#pragma unroll
  for (int it = 0; it < 2; it++) {
    int c = it * 256 + tid;
    int row = c >> 2, kc = (c & 3) * 8;
    ga[it] = Ab + (size_t)(m0 + row) * LDK + kc;
    gb[it] = Wb + (size_t)(n0 + row) * LDK + kc;
    lofs[it] = c * 8;
  }
#pragma unroll
  for (int it = 0; it < 2; it++) {
    glds16(&As[0][lofs[it]], ga[it]);
    glds16(&Bs[0][lofs[it]], gb[it]);
  }
  f4 acc[4][4] = {};
  int nk = KS >> 5;
  int cur = 0;
  __syncthreads();
  for (int t = 0; t < nk; t++) {
    if (t + 1 < nk) {
      int ko = (t + 1) * 32;
#pragma unroll
      for (int it = 0; it < 2; it++) {
        glds16(&As[cur ^ 1][lofs[it]], ga[it] + ko);
        glds16(&Bs[cur ^ 1][lofs[it]], gb[it] + ko);
      }
    }
    bf8 af[4], bfr[4];
#pragma unroll
    for (int mi = 0; mi < 4; mi++)
      af[mi] = ld8(&As[cur][(wr * 64 + mi * 16 + ml) * 32 + quad * 8]);
#pragma unroll
    for (int ni = 0; ni < 4; ni++)
      bfr[ni] = ld8(&Bs[cur][(wc * 64 + ni * 16 + ml) * 32 + quad * 8]);
#pragma unroll
    for (int mi = 0; mi < 4; mi++)
#pragma unroll
      for (int ni = 0; ni < 4; ni++)
        acc[mi][ni] = MFMA(af[mi], bfr[ni], acc[mi][ni]);
    __syncthreads();
    cur ^= 1;
  }
#pragma unroll
  for (int mi = 0; mi < 4; mi++)
#pragma unroll
    for (int ni = 0; ni < 4; ni++)
#pragma unroll
      for (int r = 0; r < 4; r++) {
        int row = m0 + wr * 64 + mi * 16 + quad * 4 + r;
        int col = n0 + wc * 64 + ni * 16 + ml;
        P[(size_t)row * N + col] = acc[mi][ni][r];
      }
}

// ------- MFMA GEMM, BM=64 x BN=128 variant, double-buffered ---------------
template <int ODT, int EPI>
__global__ __launch_bounds__(256) void gemm_lds64(const bf16* __restrict__ A,
                                                  const bf16* __restrict__ W,
                                                  const float* __restrict__ bias,
                                                  const float* __restrict__ res,
                                                  void* __restrict__ outp,
                                                  int M, int N, int K) {
  __shared__ bf16 As[2][64 * 32];
  __shared__ bf16 Bs[2][128 * 32];
  int tid = threadIdx.x;
  int lane = tid & 63, wv = tid >> 6;
  int ml = lane & 15, quad = lane >> 4;
  int wr = wv & 1, wc = wv >> 1;        // wave tile: 32 rows x 64 cols
  int m0 = blockIdx.x * 64, n0 = blockIdx.y * 128;
  const bf16* gaA;
  const bf16* gb[2];
  int lofA, lofs[2];
  {
    int c = tid;                        // A: 256 chunks
    int row = c >> 2, kc = (c & 3) * 8;
    gaA = A + (size_t)(m0 + row) * K + kc;
    lofA = c * 8;
  }
#pragma unroll
  for (int it = 0; it < 2; it++) {      // B: 512 chunks
    int c = it * 256 + tid;
    int row = c >> 2, kc = (c & 3) * 8;
    gb[it] = W + (size_t)(n0 + row) * K + kc;
    lofs[it] = c * 8;
  }
  glds16(&As[0][lofA], gaA);
#pragma unroll
  for (int it = 0; it < 2; it++) glds16(&Bs[0][lofs[it]], gb[it]);
  f4 acc[2][4] = {};
  int nk = K >> 5;
  int cur = 0;
  __syncthreads();
  for (int t = 0; t < nk; t++) {
    if (t + 1 < nk) {
      int ko = (t + 1) * 32;
      glds16(&As[cur ^ 1][lofA], gaA + ko);
#pragma unroll
      for (int it = 0; it < 2; it++) glds16(&Bs[cur ^ 1][lofs[it]], gb[it] + ko);
    }
    bf8 af[2], bfr[4];
#pragma unroll
    for (int mi = 0; mi < 2; mi++)
      af[mi] = ld8(&As[cur][(wr * 32 + mi * 16 + ml) * 32 + quad * 8]);
#pragma unroll
    for (int ni = 0; ni < 4; ni++)
      bfr[ni] = ld8(&Bs[cur][(wc * 64 + ni * 16 + ml) * 32 + quad * 8]);
#pragma unroll
    for (int mi = 0; mi < 2; mi++)
#pragma unroll
      for (int ni = 0; ni < 4; ni++)
        acc[mi][ni] = MFMA(af[mi], bfr[ni], acc[mi][ni]);
    __syncthreads();
    cur ^= 1;
  }
#pragma unroll
  for (int mi = 0; mi < 2; mi++)
#pragma unroll
    for (int ni = 0; ni < 4; ni++)
#pragma unroll
      for (int r = 0; r < 4; r++) {
        int row = m0 + wr * 32 + mi * 16 + quad * 4 + r;
        int col = n0 + wc * 64 + ni * 16 + ml;
        size_t idx = (size_t)row * N + col;
        float v = acc[mi][ni][r] + bias[col];
        if (EPI == 1) v = gelu_f(v);
        if (EPI == 2) v += res[idx];
        if (ODT == 1) ((bf16*)outp)[idx] = f2b(v);
        else ((float*)outp)[idx] = v;
      }
}

// ---------------- V transpose: VT[b,h,d,s] = qkv[b,s,2D + h*64 + d] --------
__global__ __launch_bounds__(256) void vtrans(const bf16* __restrict__ qkv,
                                              bf16* __restrict__ VT) {
  int bid = blockIdx.x;
  int st = bid % (SS / 64);
  int h = (bid / (SS / 64)) % NHEAD;
  int b = bid / ((SS / 64) * NHEAD);
  __shared__ bf16 tile[64][65];
  int s0 = st * 64;
  int tid = threadIdx.x;
  for (int it = 0; it < 16; it++) {
    int sl = it * 4 + (tid >> 6), dl = tid & 63;
    tile[sl][dl] = qkv[(size_t)(b * SS + s0 + sl) * (3 * DDIM) + 2 * DDIM + h * 64 + dl];
  }
  __syncthreads();
  for (int it = 0; it < 16; it++) {
    int dl = it * 4 + (tid >> 6), sl = tid & 63;
    VT[((size_t)(b * NHEAD + h) * 64 + dl) * SS + s0 + sl] = tile[sl][dl];
  }
}

// ---- Flash attention v8: double-buffered block-shared K/V staging. Next
// tile's glds16 issued BEFORE both phase computations; single barrier/tile.
__device__ __forceinline__ void phase_tile(int kt, int q0, int nkt,
                                           const bf8* qf, f4* oacc,
                                           float* m_r, float* l_r,
                                           const bf16* __restrict__ Ks,
                                           const bf16* __restrict__ Vs,
                                           bf16 (*pl)[72], int ml, int quad) {
  if (kt >= nkt) return;                 // block-uniform condition
  const float SC = 0.125f * 1.44269504089f;  // 1/sqrt(64) * log2(e)
  int k0 = kt * 64;
  f4 sacc[4] = {{0,0,0,0},{0,0,0,0},{0,0,0,0},{0,0,0,0}};
#pragma unroll
  for (int kk = 0; kk < 2; kk++)
#pragma unroll
    for (int c = 0; c < 4; c++) {
      int chunk = ((c * 16 + ml) << 3) + ((kk * 4 + quad) ^ (ml & 7));
      bf8 kf = ld8(&Ks[chunk * 8]);
      sacc[c] = MFMA(qf[kk], kf, sacc[c]);
    }
  float sv[4][4];
#pragma unroll
  for (int c = 0; c < 4; c++)
#pragma unroll
    for (int r = 0; r < 4; r++) sv[c][r] = sacc[c][r] * SC;
  if (kt == nkt - 1) {                   // diagonal tile: causal mask
#pragma unroll
    for (int c = 0; c < 4; c++)
#pragma unroll
      for (int r = 0; r < 4; r++) {
        int qi = q0 + quad * 4 + r;
        int kj = k0 + c * 16 + ml;
        if (kj > qi) sv[c][r] = -1e9f;
      }
  }
  float alpha[4];
#pragma unroll
  for (int r = 0; r < 4; r++) {
    float mx = fmaxf(fmaxf(sv[0][r], sv[1][r]), fmaxf(sv[2][r], sv[3][r]));
#pragma unroll
    for (int off = 1; off < 16; off <<= 1) mx = fmaxf(mx, __shfl_xor(mx, off));
    float mn = fmaxf(m_r[r], mx);
    float rs = 0.0f;
#pragma unroll
    for (int c = 0; c < 4; c++) {
      float p = fexp2(sv[c][r] - mn);
      sv[c][r] = p;
      rs += p;
    }
#pragma unroll
    for (int off = 1; off < 16; off <<= 1) rs += __shfl_xor(rs, off);
    alpha[r] = fexp2(m_r[r] - mn);
    l_r[r] = l_r[r] * alpha[r] + rs;
    m_r[r] = mn;
  }
#pragma unroll
  for (int c = 0; c < 4; c++)
#pragma unroll
    for (int r = 0; r < 4; r++) oacc[c][r] *= alpha[r];
  // C-layout -> A-layout via per-wave LDS slice (padded to 72: conflict-free,
  // 144 B row stride keeps 16 B alignment)
#pragma unroll
  for (int c = 0; c < 4; c++)
#pragma unroll
    for (int r = 0; r < 4; r++)
      pl[quad * 4 + r][c * 16 + ml] = f2b(sv[c][r]);
  bf8 pf[2];
#pragma unroll
  for (int kk = 0; kk < 2; kk++) pf[kk] = ld8(&pl[ml][kk * 32 + quad * 8]);
#pragma unroll
  for (int c = 0; c < 4; c++)
#pragma unroll
    for (int kk = 0; kk < 2; kk++) {
      int chunk = ((c * 16 + ml) << 3) + ((kk * 4 + quad) ^ (ml & 7));
      bf8 vf = ld8(&Vs[chunk * 8]);
      oacc[c] = MFMA(pf[kk], vf, oacc[c]);
    }
}

__global__ __launch_bounds__(256) void flash_attn(const bf16* __restrict__ qkv,
                                                  const bf16* __restrict__ VT,
                                                  bf16* __restrict__ obuf) {
  int bid = blockIdx.x;                 // grid: BB*NHEAD*16 = 512 blocks
  int blk = bid & 15;
  int h = (bid >> 4) & 15;
  int b = bid >> 8;
  int tid = threadIdx.x;
  int wv = tid >> 6, lane = tid & 63;
  int ml = lane & 15, quad = lane >> 4;
  int idx0 = blk * 4 + wv;              // phase-0 subtile (16 Q rows)
  int idx1 = 127 - idx0;                // phase-1 (antithetic)
  int q0a = idx0 * 16, q0b = idx1 * 16;
  int nkt0 = blk + 1;                   // block-uniform (idx0>>2 == blk)
  int nkt1 = 32 - blk;                  // block-uniform; nkt1 >= nkt0
  int maxn = nkt1;

  __shared__ __align__(16) bf16 Ks[2][64 * 64];
  __shared__ __align__(16) bf16 Vs[2][64 * 64];
  __shared__ __align__(16) bf16 plds[4][16][72];
  bf16 (*pl)[72] = plds[wv];

  bf8 qfa[2], qfb[2];
#pragma unroll
  for (int kk = 0; kk < 2; kk++) {
    qfa[kk] = ld8(qkv + (size_t)(b * SS + q0a + ml) * (3 * DDIM) + h * 64 + kk * 32 + quad * 8);
    qfb[kk] = ld8(qkv + (size_t)(b * SS + q0b + ml) * (3 * DDIM) + h * 64 + kk * 32 + quad * 8);
  }
  f4 oacca[4] = {{0,0,0,0},{0,0,0,0},{0,0,0,0},{0,0,0,0}};
  f4 oaccb[4] = {{0,0,0,0},{0,0,0,0},{0,0,0,0},{0,0,0,0}};
  float ma[4], la[4], mb[4], lb[4];
#pragma unroll
  for (int r = 0; r < 4; r++) {
    ma[r] = -1e30f; la[r] = 0.0f;
    mb[r] = -1e30f; lb[r] = 0.0f;
  }

  const bf16* kglob = qkv + (size_t)b * SS * (3 * DDIM) + DDIM + h * 64;
  const bf16* vglob = VT + (size_t)(b * NHEAD + h) * 64 * SS;

  // prologue: stage tile 0 into buffer 0 (swizzled SOURCE, lane-linear dest)
#pragma unroll
  for (int it = 0; it < 2; it++) {
    int lam = it * 256 + tid;
    int row = lam >> 3;
    int ch = (lam & 7) ^ (row & 7);
    glds16(&Ks[0][lam * 8], kglob + (size_t)row * (3 * DDIM) + ch * 8);
    glds16(&Vs[0][lam * 8], vglob + (size_t)row * SS + ch * 8);
  }
  __syncthreads();
  int cur = 0;
  for (int kt = 0; kt < maxn; kt++) {
    if (kt + 1 < maxn) {                // prefetch next K/V tile
      int k0n = (kt + 1) * 64;
#pragma unroll
      for (int it = 0; it < 2; it++) {
        int lam = it * 256 + tid;
        int row = lam >> 3;
        int ch = (lam & 7) ^ (row & 7);
        glds16(&Ks[cur ^ 1][lam * 8], kglob + (size_t)(k0n + row) * (3 * DDIM) + ch * 8);
        glds16(&Vs[cur ^ 1][lam * 8], vglob + (size_t)row * SS + k0n + ch * 8);
      }
    }
    phase_tile(kt, q0a, nkt0, qfa, oacca, ma, la, Ks[cur], Vs[cur], pl, ml, quad);
    phase_tile(kt, q0b, nkt1, qfb, oaccb, mb, lb, Ks[cur], Vs[cur], pl, ml, quad);
    __syncthreads();                    // vmcnt(0)+lgkmcnt(0)+barrier
    cur ^= 1;
  }
#pragma unroll
  for (int c = 0; c < 4; c++)
#pragma unroll
    for (int r = 0; r < 4; r++) {
      int rowa = q0a + quad * 4 + r;
      int rowb = q0b + quad * 4 + r;
      obuf[(size_t)(b * SS + rowa) * DDIM + h * 64 + c * 16 + ml] =
          f2b(oacca[c][r] / la[r]);
      obuf[(size_t)(b * SS + rowb) * DDIM + h * 64 + c * 16 + ml] =
          f2b(oaccb[c][r] / lb[r]);
    }
}

// ---------------- final: out = y + P0 + P1 + b2 + mhc(XD) ----------------
__global__ __launch_bounds__(256) void final_k(const float* __restrict__ y,
                                               const float* __restrict__ P0,
                                               const float* __restrict__ P1,
                                               const float* __restrict__ bias,
                                               const float* __restrict__ xd,
                                               const float* __restrict__ hres,
                                               const float* __restrict__ gres,
                                               float* __restrict__ out) {
  int row = blockIdx.x;  // [B*S]
  int b = row / SS;
  int tid = threadIdx.x;
  __shared__ float cf[8][8];
  if (tid < 64) cf[tid >> 3][tid & 7] = hres[tid] * gres[b * NSTR + (tid & 7)];
  __syncthreads();
  const float* yr = y + (size_t)row * DDIM;
  const float* p0 = P0 + (size_t)row * DDIM;
  const float* p1 = P1 + (size_t)row * DDIM;
  const float* xr = xd + (size_t)row * DDIM;
  float* o = out + (size_t)row * DDIM;
  for (int i = tid; i < DDIM; i += 256) {
    int m = i >> 7, dd = i & 127;
    float acc = yr[i] + p0[i] + p1[i] + bias[i];
#pragma unroll
    for (int n = 0; n < 8; n++) acc += cf[m][n] * xr[n * SDIMC + dd];
    o[i] = acc;
  }
}

extern "C" void kernel_launch(void* const* d_in, const int* in_sizes, int n_in,
                              void* d_out, int out_size, void* d_ws, size_t ws_size,
                              hipStream_t stream) {
  const float* x     = (const float*)d_in[0];
  const float* decay = (const float*)d_in[3];
  const float* gw    = (const float*)d_in[4];
  const float* gb    = (const float*)d_in[5];
  const float* phi   = (const float*)d_in[6];
  const float* ln1   = (const float*)d_in[7];
  const float* ln2   = (const float*)d_in[8];
  const float* w1    = (const float*)d_in[9];
  const float* b1    = (const float*)d_in[10];
  const float* w2    = (const float*)d_in[11];
  const float* b2    = (const float*)d_in[12];
  const float* ipw   = (const float*)d_in[13];
  const float* ipb   = (const float*)d_in[14];
  const float* ow    = (const float*)d_in[15];
  const float* obs   = (const float*)d_in[16];
  float* out = (float*)d_out;

  // ---- workspace layout (105 MB total) ----
  const size_t MB = 1048576ull;
  char* wsp = (char*)d_ws;
  float* SA   = (float*)(wsp);                 // 128 KB  chunk states / sums
  float* SIN  = (float*)(wsp + 131072ull);     // 128 KB  incoming states
  float* GRES = (float*)(wsp + 262144ull);     // 64 B
  float* HRES = (float*)(wsp + 262208ull);     // 256 B
  float* XD   = (float*)(wsp + 1 * MB);        // 16 MB   x_delta (f32), live to end
  float* AO   = (float*)(wsp + 17 * MB);       // 16 MB   y = x_delta + attn_out
  bf16*  NORM = (bf16*)(wsp + 33 * MB);        // 8 MB    normed/normed2 (dead after ffn1)
  bf16*  OB   = (bf16*)(wsp + 41 * MB);        // 8 MB    attn out (dead after outproj)
  bf16*  QKV  = (bf16*)(wsp + 49 * MB);        // 24 MB   (dead after flash)
  bf16*  VT   = (bf16*)(wsp + 73 * MB);        // 8 MB    (dead after flash)
  bf16*  HB   = (bf16*)(wsp + 49 * MB);        // 32 MB   gelu hidden, ALIASES QKV+VT
  bf16*  WIPW = (bf16*)(wsp + 81 * MB);        // 6 MB    in_proj_w bf16 (dead after qkv)
  bf16*  WOW  = (bf16*)(wsp + 87 * MB);        // 2 MB    out_w bf16 (dead after outproj)
  bf16*  W1B  = (bf16*)(wsp + 89 * MB);        // 8 MB    w1 bf16 (dead after ffn1)
  bf16*  W2B  = (bf16*)(wsp + 97 * MB);        // 8 MB    w2 bf16 (live thru ffn2)
  // ffn2 split-K partials (f32, 16 MB each), live from ffn2 thru final_k:
  // PK0 over NORM+OB (33-49 MB, dead), PK1 over WIPW/WOW/W1B (81-97 MB, dead)
  float* PK0  = (float*)(wsp + 33 * MB);
  float* PK1  = (float*)(wsp + 81 * MB);

  // 0: convert all GEMM weights f32 -> bf16 (single launch, float4 -> 8B pack)
  cvt_all<<<dim3(12 * DDIM * DDIM / 1024), dim3(256), 0, stream>>>(
      ipw, ow, w1, w2, WIPW, WOW, W1B, W2B);

  // 1-3: delta operator scan
  delta_passA<<<dim3(BB * NCH * DDIM / 256), dim3(256), 0, stream>>>(x, decay, SA);
  delta_passB<<<dim3(BB * DDIM / 256), dim3(256), 0, stream>>>(SA, decay, SIN);
  delta_passC<<<dim3(BB * NCH * DDIM / 256), dim3(256), 0, stream>>>(x, decay, SIN, XD, SA);
  // 4: gates + sinkhorn
  gates_sinkhorn<<<dim3(1), dim3(1024), 0, stream>>>(SA, gw, gb, phi, GRES, HRES);
  // 5: rmsnorm1 (XD -> NORM)
  rmsnorm_k<<<dim3(BB * SS), dim3(256), 0, stream>>>(XD, ln1, NORM);
  // 6: qkv = NORM @ in_proj_w.T + in_proj_b   [4096 x 3072]
  gemm_lds<1, 0><<<dim3(32, 24), dim3(256), 0, stream>>>(NORM, WIPW, ipb, nullptr,
                                                         QKV, BB * SS, 3 * DDIM, DDIM);
  // 7: V transpose
  vtrans<<<dim3(BB * NHEAD * (SS / 64)), dim3(256), 0, stream>>>(QKV, VT);
  // 8: flash attention -> OB (double-buffered block-shared LDS K/V)
  flash_attn<<<dim3(BB * NHEAD * 16), dim3(256), 0, stream>>>(QKV, VT, OB);
  // 9: out-proj + residual(XD) -> AO (= y)
  gemm_lds64<0, 2><<<dim3(64, 8), dim3(256), 0, stream>>>(OB, WOW, obs, XD,
                                                          AO, BB * SS, DDIM, DDIM);
  // 10: rmsnorm2 (AO -> NORM)
  rmsnorm_k<<<dim3(BB * SS), dim3(256), 0, stream>>>(AO, ln2, NORM);
  // 11: ffn1 + gelu -> HB   [4096 x 4096]  (HB aliases dead QKV/VT)
  gemm_lds<1, 1><<<dim3(32, 32), dim3(256), 0, stream>>>(NORM, W1B, b1, nullptr,
                                                         HB, BB * SS, 4 * DDIM, DDIM);
  // 12: ffn2 split-K=2, ONE launch (512 co-resident blocks) -> PK0/PK1
  gemm_part2<<<dim3(32, 8, 2), dim3(256), 0, stream>>>(HB, W2B, PK0, PK1,
                                                       BB * SS, DDIM, 2 * DDIM, 4 * DDIM);
  // 13: final out = y + PK0 + PK1 + b2 + mhc(XD)  (ffn2 epilogue fused here)
  final_k<<<dim3(BB * SS), dim3(256), 0, stream>>>(AO, PK0, PK1, b2, XD,
                                                   HRES, GRES, out);
}

// Round 2
// 443.562 us; speedup vs baseline: 1.0628x; 1.0001x over previous
//
#include <hip/hip_runtime.h>
#include <hip/hip_bf16.h>
#include <math.h>

// Problem constants
#define BB 2
#define SS 2048
#define DDIM 1024
#define NHEAD 16
#define NSTR 8
#define SDIMC 128
#define NCH 16      // chunks for delta scan
#define CLEN 128    // chunk length
#define EPSV 1e-6f

using bf16 = __hip_bfloat16;
typedef __attribute__((ext_vector_type(8))) __bf16 bf8;
typedef __attribute__((ext_vector_type(4))) __bf16 bf4v;
typedef __attribute__((ext_vector_type(4))) float f4;

__device__ __forceinline__ bf16 f2b(float v) { return __float2bfloat16(v); }
__device__ __forceinline__ bf8 ld8(const bf16* p) { return *(const bf8*)p; }
__device__ __forceinline__ f4 MFMA(bf8 a, bf8 b, f4 c) {
  return __builtin_amdgcn_mfma_f32_16x16x32_bf16(a, b, c, 0, 0, 0);
}
__device__ __forceinline__ float sigm(float x) { return 1.0f / (1.0f + expf(-x)); }
__device__ __forceinline__ float fexp2(float x) { return __builtin_amdgcn_exp2f(x); }

// fast gelu (exact-erf form) via Abramowitz-Stegun 7.1.26: |erf err| <= 1.5e-7,
// far below bf16 store rounding. hw rcp + hw exp2 instead of libm erff.
__device__ __forceinline__ float gelu_f(float v) {
  float x = v * 0.70710678118654752f;
  float ax = fabsf(x);
  float t = __builtin_amdgcn_rcpf(1.0f + 0.3275911f * ax);
  float p = ((((1.061405429f * t - 1.453152027f) * t + 1.421413741f) * t
              - 0.284496736f) * t + 0.254829592f) * t;
  float e = 1.0f - p * fexp2(-ax * ax * 1.4426950408889634f);
  e = copysignf(e, x);
  return 0.5f * v * (1.0f + e);
}

// async global->LDS 16B copy (m97 pattern; LDS dest must be uniform + lane*16)
__device__ __forceinline__ void glds16(bf16* l, const bf16* g) {
  __builtin_amdgcn_global_load_lds(
      (const __attribute__((address_space(1))) unsigned int*)g,
      (__attribute__((address_space(3))) unsigned int*)l, 16, 0, 0);
}

// ---------------- f32 -> bf16 weight conversion (all 4 weights, one launch) --
__global__ __launch_bounds__(256) void cvt_all(const float* __restrict__ ipw,
                                               const float* __restrict__ ow,
                                               const float* __restrict__ w1,
                                               const float* __restrict__ w2,
                                               bf16* __restrict__ WIPW,
                                               bf16* __restrict__ WOW,
                                               bf16* __restrict__ W1B,
                                               bf16* __restrict__ W2B) {
  const int S1 = 3 * DDIM * DDIM, S2 = S1 + DDIM * DDIM,
            S3 = S2 + 4 * DDIM * DDIM;
  int i4 = (blockIdx.x * 256 + threadIdx.x) * 4;   // grid covers 12.58M elems
  const float* src;
  bf16* dst;
  int off;
  if (i4 < S1)      { src = ipw; dst = WIPW; off = i4; }
  else if (i4 < S2) { src = ow;  dst = WOW;  off = i4 - S1; }
  else if (i4 < S3) { src = w1;  dst = W1B;  off = i4 - S2; }
  else              { src = w2;  dst = W2B;  off = i4 - S3; }
  float4 v = *(const float4*)(src + off);
  bf4v o;
  o[0] = (__bf16)v.x; o[1] = (__bf16)v.y; o[2] = (__bf16)v.z; o[3] = (__bf16)v.w;
  *(bf4v*)(dst + off) = o;                         // one 8B store, fully packed
}

// ---------------- Delta operator: 3-pass chunked affine scan ----------------
__global__ __launch_bounds__(256) void delta_passA(const float* __restrict__ x,
                                                   const float* __restrict__ decay,
                                                   float* __restrict__ SA) {
  int idx = blockIdx.x * 256 + threadIdx.x;      // [b][c][d]
  int d = idx % DDIM;
  int c = (idx / DDIM) % NCH;
  int b = idx / (DDIM * NCH);
  float beta = sigm(decay[d]);
  float omb = 1.0f - beta;
  const float* xp = x + ((size_t)(b * SS + c * CLEN)) * DDIM + d;
  float s = 0.0f;
  for (int j = 0; j < CLEN; j++) {
    float xv = xp[(size_t)j * DDIM];
    s = beta * s + omb * xv;
  }
  SA[idx] = s;
}

__global__ __launch_bounds__(256) void delta_passB(const float* __restrict__ SA,
                                                   const float* __restrict__ decay,
                                                   float* __restrict__ SIN) {
  int idx = blockIdx.x * 256 + threadIdx.x;      // [b][d]
  int d = idx % DDIM;
  int b = idx / DDIM;
  float beta = sigm(decay[d]);
  float p = beta;
  for (int i = 0; i < 7; i++) p *= p;            // beta^128
  float s = 0.0f;
  for (int c = 0; c < NCH; c++) {
    SIN[(b * NCH + c) * DDIM + d] = s;
    s = p * s + SA[(b * NCH + c) * DDIM + d];
  }
}

__global__ __launch_bounds__(256) void delta_passC(const float* __restrict__ x,
                                                   const float* __restrict__ decay,
                                                   const float* __restrict__ SIN,
                                                   float* __restrict__ XD,
                                                   float* __restrict__ SA) {
  int idx = blockIdx.x * 256 + threadIdx.x;      // [b][c][d]
  int d = idx % DDIM;
  int c = (idx / DDIM) % NCH;
  int b = idx / (DDIM * NCH);
  float beta = sigm(decay[d]);
  float omb = 1.0f - beta;
  const float* xp = x + ((size_t)(b * SS + c * CLEN)) * DDIM + d;
  float* xdp = XD + ((size_t)(b * SS + c * CLEN)) * DDIM + d;
  float s = SIN[idx];
  float sum = 0.0f;
  for (int j = 0; j < CLEN; j++) {
    float xv = xp[(size_t)j * DDIM];
    float o = xv - s;
    xdp[(size_t)j * DDIM] = o;
    sum += o;
    s = beta * s + omb * xv;
  }
  SA[idx] = sum;
}

// ---------------- gates (g_res) + sinkhorn ----------------
__global__ __launch_bounds__(1024) void gates_sinkhorn(const float* __restrict__ SA,
                                                       const float* __restrict__ gw,
                                                       const float* __restrict__ gb,
                                                       const float* __restrict__ phi,
                                                       float* __restrict__ gres,
                                                       float* __restrict__ hres) {
  int tid = threadIdx.x;
  int wave = tid >> 6, lane = tid & 63;
  int b = wave >> 3, j = wave & 7;               // 16 waves: (b, gate j)
  float acc = 0.0f;
  for (int d = lane; d < DDIM; d += 64) {
    float xs = 0.0f;
    for (int c = 0; c < NCH; c++) xs += SA[(b * NCH + c) * DDIM + d];
    xs *= (1.0f / (float)SS);
    acc += xs * gw[(2 * NSTR + j) * DDIM + d];
  }
  for (int off = 32; off > 0; off >>= 1) acc += __shfl_down(acc, off);
  if (lane == 0) gres[b * NSTR + j] = sigm(acc + gb[2 * NSTR + j]);
  __syncthreads();
  if (tid == 0) {
    float Km[8][8];
    for (int i = 0; i < 8; i++)
      for (int jj = 0; jj < 8; jj++) Km[i][jj] = expf(phi[i * 8 + jj]);
    for (int it = 0; it < 15; it++) {
      for (int i = 0; i < 8; i++) {
        float rs = 0.0f;
        for (int jj = 0; jj < 8; jj++) rs += Km[i][jj];
        float inv = 1.0f / rs;
        for (int jj = 0; jj < 8; jj++) Km[i][jj] *= inv;
      }
      for (int jj = 0; jj < 8; jj++) {
        float cs = 0.0f;
        for (int i = 0; i < 8; i++) cs += Km[i][jj];
        float inv = 1.0f / cs;
        for (int i = 0; i < 8; i++) Km[i][jj] *= inv;
      }
    }
    for (int i = 0; i < 8; i++)
      for (int jj = 0; jj < 8; jj++) hres[i * 8 + jj] = Km[i][jj];
  }
}

// ---------------- RMSNorm (f32 in -> bf16 out) ----------------
__global__ __launch_bounds__(256) void rmsnorm_k(const float* __restrict__ in,
                                                 const float* __restrict__ w,
                                                 bf16* __restrict__ out) {
  int row = blockIdx.x;
  const float* r = in + (size_t)row * DDIM;
  int tid = threadIdx.x;
  float ss = 0.0f;
  for (int i = tid; i < DDIM; i += 256) {
    float v = r[i];
    ss += v * v;
  }
  for (int off = 32; off > 0; off >>= 1) ss += __shfl_down(ss, off);
  __shared__ float red[4];
  if ((tid & 63) == 0) red[tid >> 6] = ss;
  __syncthreads();
  float tot = red[0] + red[1] + red[2] + red[3];
  float sc = rsqrtf(tot / (float)DDIM + EPSV);
  bf16* o = out + (size_t)row * DDIM;
  for (int i = tid; i < DDIM; i += 256) o[i] = f2b(r[i] * sc * w[i]);
}

// ------- MFMA GEMM, 128x128 tile, BK=32, DOUBLE-BUFFERED single-barrier loop.
// T3-minimal recipe: issue next tile's global_load_lds BEFORE ds_read+MFMA of
// current tile; one __syncthreads (vmcnt(0)+lgkmcnt(0)+barrier) per K-step.
// ODT: 0=f32 out, 1=bf16 out.  EPI: 0=none, 1=gelu(exact erf), 2=add residual
template <int ODT, int EPI>
__global__ __launch_bounds__(256) void gemm_lds(const bf16* __restrict__ A,
                                                const bf16* __restrict__ W,
                                                const float* __restrict__ bias,
                                                const float* __restrict__ res,
                                                void* __restrict__ outp,
                                                int M, int N, int K) {
  __shared__ bf16 As[2][128 * 32];
  __shared__ bf16 Bs[2][128 * 32];
  int tid = threadIdx.x;
  int lane = tid & 63, wv = tid >> 6;
  int ml = lane & 15, quad = lane >> 4;
  int wr = wv >> 1, wc = wv & 1;
  int m0 = blockIdx.x * 128, n0 = blockIdx.y * 128;
  // per-thread staging addresses (2 chunks each of A,B)
  const bf16* ga[2];
  const bf16* gb[2];
  int lofs[2];
#pragma unroll
  for (int it = 0; it < 2; it++) {
    int c = it * 256 + tid;             // 512 16B-chunks per tile
    int row = c >> 2, kc = (c & 3) * 8;
    ga[it] = A + (size_t)(m0 + row) * K + kc;
    gb[it] = W + (size_t)(n0 + row) * K + kc;
    lofs[it] = c * 8;
  }
  // prologue: stage tile 0 into buffer 0
#pragma unroll
  for (int it = 0; it < 2; it++) {
    glds16(&As[0][lofs[it]], ga[it]);
    glds16(&Bs[0][lofs[it]], gb[it]);
  }
  f4 acc[4][4] = {};
  int nk = K >> 5;
  int cur = 0;
  __syncthreads();
  for (int t = 0; t < nk; t++) {
    if (t + 1 < nk) {                    // prefetch tile t+1 into other buffer
      int ko = (t + 1) * 32;
#pragma unroll
      for (int it = 0; it < 2; it++) {
        glds16(&As[cur ^ 1][lofs[it]], ga[it] + ko);
        glds16(&Bs[cur ^ 1][lofs[it]], gb[it] + ko);
      }
    }
    bf8 af[4], bfr[4];
#pragma unroll
    for (int mi = 0; mi < 4; mi++)
      af[mi] = ld8(&As[cur][(wr * 64 + mi * 16 + ml) * 32 + quad * 8]);
#pragma unroll
    for (int ni = 0; ni < 4; ni++)
      bfr[ni] = ld8(&Bs[cur][(wc * 64 + ni * 16 + ml) * 32 + quad * 8]);
#pragma unroll
    for (int mi = 0; mi < 4; mi++)
#pragma unroll
      for (int ni = 0; ni < 4; ni++)
        acc[mi][ni] = MFMA(af[mi], bfr[ni], acc[mi][ni]);
    __syncthreads();                     // vmcnt(0)+lgkmcnt(0)+barrier
    cur ^= 1;
  }
#pragma unroll
  for (int mi = 0; mi < 4; mi++)
#pragma unroll
    for (int ni = 0; ni < 4; ni++)
#pragma unroll
      for (int r = 0; r < 4; r++) {
        int row = m0 + wr * 64 + mi * 16 + quad * 4 + r;
        int col = n0 + wc * 64 + ni * 16 + ml;
        size_t idx = (size_t)row * N + col;
        float v = acc[mi][ni][r] + bias[col];
        if (EPI == 1) v = gelu_f(v);
        if (EPI == 2) v += res[idx];
        if (ODT == 1) ((bf16*)outp)[idx] = f2b(v);
        else ((float*)outp)[idx] = v;
      }
}

// ------- ffn2 split-K=2, ONE launch, grid (32,8,2): z picks K-slice+buffer ---
// same double-buffered single-barrier structure
__global__ __launch_bounds__(256) void gemm_part2(const bf16* __restrict__ A,
                                                  const bf16* __restrict__ W,
                                                  float* __restrict__ P0,
                                                  float* __restrict__ P1,
                                                  int M, int N, int KS, int LDK) {
  __shared__ bf16 As[2][128 * 32];
  __shared__ bf16 Bs[2][128 * 32];
  int tid = threadIdx.x;
  int lane = tid & 63, wv = tid >> 6;
  int ml = lane & 15, quad = lane >> 4;
  int wr = wv >> 1, wc = wv & 1;
  int m0 = blockIdx.x * 128, n0 = blockIdx.y * 128;
  const bf16* Ab = A + blockIdx.z * KS;
  const bf16* Wb = W + blockIdx.z * KS;
  float* P = blockIdx.z ? P1 : P0;
  const bf16* ga[2];
  const bf16* gb[2];
  int lofs[2];
#pragma unroll
  for (int it = 0; it < 2; it++) {
    int c = it * 256 + tid;
    int row = c >> 2, kc = (c & 3) * 8;
    ga[it] = Ab + (size_t)(m0 + row) * LDK + kc;
    gb[it] = Wb + (size_t)(n0 + row) * LDK + kc;
    lofs[it] = c * 8;
  }
#pragma unroll
  for (int it = 0; it < 2; it++) {
    glds16(&As[0][lofs[it]], ga[it]);
    glds16(&Bs[0][lofs[it]], gb[it]);
  }
  f4 acc[4][4] = {};
  int nk = KS >> 5;
  int cur = 0;
  __syncthreads();
  for (int t = 0; t < nk; t++) {
    if (t + 1 < nk) {
      int ko = (t + 1) * 32;
#pragma unroll
      for (int it = 0; it < 2; it++) {
        glds16(&As[cur ^ 1][lofs[it]], ga[it] + ko);
        glds16(&Bs[cur ^ 1][lofs[it]], gb[it] + ko);
      }
    }
    bf8 af[4], bfr[4];
#pragma unroll
    for (int mi = 0; mi < 4; mi++)
      af[mi] = ld8(&As[cur][(wr * 64 + mi * 16 + ml) * 32 + quad * 8]);
#pragma unroll
    for (int ni = 0; ni < 4; ni++)
      bfr[ni] = ld8(&Bs[cur][(wc * 64 + ni * 16 + ml) * 32 + quad * 8]);
#pragma unroll
    for (int mi = 0; mi < 4; mi++)
#pragma unroll
      for (int ni = 0; ni < 4; ni++)
        acc[mi][ni] = MFMA(af[mi], bfr[ni], acc[mi][ni]);
    __syncthreads();
    cur ^= 1;
  }
#pragma unroll
  for (int mi = 0; mi < 4; mi++)
#pragma unroll
    for (int ni = 0; ni < 4; ni++)
#pragma unroll
      for (int r = 0; r < 4; r++) {
        int row = m0 + wr * 64 + mi * 16 + quad * 4 + r;
        int col = n0 + wc * 64 + ni * 16 + ml;
        P[(size_t)row * N + col] = acc[mi][ni][r];
      }
}

// ------- MFMA GEMM, BM=64 x BN=128 variant, double-buffered ---------------
template <int ODT, int EPI>
__global__ __launch_bounds__(256) void gemm_lds64(const bf16* __restrict__ A,
                                                  const bf16* __restrict__ W,
                                                  const float* __restrict__ bias,
                                                  const float* __restrict__ res,
                                                  void* __restrict__ outp,
                                                  int M, int N, int K) {
  __shared__ bf16 As[2][64 * 32];
  __shared__ bf16 Bs[2][128 * 32];
  int tid = threadIdx.x;
  int lane = tid & 63, wv = tid >> 6;
  int ml = lane & 15, quad = lane >> 4;
  int wr = wv & 1, wc = wv >> 1;        // wave tile: 32 rows x 64 cols
  int m0 = blockIdx.x * 64, n0 = blockIdx.y * 128;
  const bf16* gaA;
  const bf16* gb[2];
  int lofA, lofs[2];
  {
    int c = tid;                        // A: 256 chunks
    int row = c >> 2, kc = (c & 3) * 8;
    gaA = A + (size_t)(m0 + row) * K + kc;
    lofA = c * 8;
  }
#pragma unroll
  for (int it = 0; it < 2; it++) {      // B: 512 chunks
    int c = it * 256 + tid;
    int row = c >> 2, kc = (c & 3) * 8;
    gb[it] = W + (size_t)(n0 + row) * K + kc;
    lofs[it] = c * 8;
  }
  glds16(&As[0][lofA], gaA);
#pragma unroll
  for (int it = 0; it < 2; it++) glds16(&Bs[0][lofs[it]], gb[it]);
  f4 acc[2][4] = {};
  int nk = K >> 5;
  int cur = 0;
  __syncthreads();
  for (int t = 0; t < nk; t++) {
    if (t + 1 < nk) {
      int ko = (t + 1) * 32;
      glds16(&As[cur ^ 1][lofA], gaA + ko);
#pragma unroll
      for (int it = 0; it < 2; it++) glds16(&Bs[cur ^ 1][lofs[it]], gb[it] + ko);
    }
    bf8 af[2], bfr[4];
#pragma unroll
    for (int mi = 0; mi < 2; mi++)
      af[mi] = ld8(&As[cur][(wr * 32 + mi * 16 + ml) * 32 + quad * 8]);
#pragma unroll
    for (int ni = 0; ni < 4; ni++)
      bfr[ni] = ld8(&Bs[cur][(wc * 64 + ni * 16 + ml) * 32 + quad * 8]);
#pragma unroll
    for (int mi = 0; mi < 2; mi++)
#pragma unroll
      for (int ni = 0; ni < 4; ni++)
        acc[mi][ni] = MFMA(af[mi], bfr[ni], acc[mi][ni]);
    __syncthreads();
    cur ^= 1;
  }
#pragma unroll
  for (int mi = 0; mi < 2; mi++)
#pragma unroll
    for (int ni = 0; ni < 4; ni++)
#pragma unroll
      for (int r = 0; r < 4; r++) {
        int row = m0 + wr * 32 + mi * 16 + quad * 4 + r;
        int col = n0 + wc * 64 + ni * 16 + ml;
        size_t idx = (size_t)row * N + col;
        float v = acc[mi][ni][r] + bias[col];
        if (EPI == 1) v = gelu_f(v);
        if (EPI == 2) v += res[idx];
        if (ODT == 1) ((bf16*)outp)[idx] = f2b(v);
        else ((float*)outp)[idx] = v;
      }
}

// ---------------- V transpose: VT[b,h,d,s] = qkv[b,s,2D + h*64 + d] --------
__global__ __launch_bounds__(256) void vtrans(const bf16* __restrict__ qkv,
                                              bf16* __restrict__ VT) {
  int bid = blockIdx.x;
  int st = bid % (SS / 64);
  int h = (bid / (SS / 64)) % NHEAD;
  int b = bid / ((SS / 64) * NHEAD);
  __shared__ bf16 tile[64][65];
  int s0 = st * 64;
  int tid = threadIdx.x;
  for (int it = 0; it < 16; it++) {
    int sl = it * 4 + (tid >> 6), dl = tid & 63;
    tile[sl][dl] = qkv[(size_t)(b * SS + s0 + sl) * (3 * DDIM) + 2 * DDIM + h * 64 + dl];
  }
  __syncthreads();
  for (int it = 0; it < 16; it++) {
    int dl = it * 4 + (tid >> 6), sl = tid & 63;
    VT[((size_t)(b * NHEAD + h) * 64 + dl) * SS + s0 + sl] = tile[sl][dl];
  }
}

// ---- Flash attention v9: v8 double-buffer + T1 XCD swizzle (each XCD owns 4
// complete (b,h) groups -> K/V L2-resident, 2MB/XCD) + complementary blk
// pairing (adjacent blocks sum to 49 tiles) + T5 setprio around MFMA.
__device__ __forceinline__ void phase_tile(int kt, int q0, int nkt,
                                           const bf8* qf, f4* oacc,
                                           float* m_r, float* l_r,
                                           const bf16* __restrict__ Ks,
                                           const bf16* __restrict__ Vs,
                                           bf16 (*pl)[72], int ml, int quad) {
  if (kt >= nkt) return;                 // block-uniform condition
  const float SC = 0.125f * 1.44269504089f;  // 1/sqrt(64) * log2(e)
  int k0 = kt * 64;
  f4 sacc[4] = {{0,0,0,0},{0,0,0,0},{0,0,0,0},{0,0,0,0}};
  __builtin_amdgcn_s_setprio(1);
#pragma unroll
  for (int kk = 0; kk < 2; kk++)
#pragma unroll
    for (int c = 0; c < 4; c++) {
      int chunk = ((c * 16 + ml) << 3) + ((kk * 4 + quad) ^ (ml & 7));
      bf8 kf = ld8(&Ks[chunk * 8]);
      sacc[c] = MFMA(qf[kk], kf, sacc[c]);
    }
  __builtin_amdgcn_s_setprio(0);
  float sv[4][4];
#pragma unroll
  for (int c = 0; c < 4; c++)
#pragma unroll
    for (int r = 0; r < 4; r++) sv[c][r] = sacc[c][r] * SC;
  if (kt == nkt - 1) {                   // diagonal tile: causal mask
#pragma unroll
    for (int c = 0; c < 4; c++)
#pragma unroll
      for (int r = 0; r < 4; r++) {
        int qi = q0 + quad * 4 + r;
        int kj = k0 + c * 16 + ml;
        if (kj > qi) sv[c][r] = -1e9f;
      }
  }
  float alpha[4];
#pragma unroll
  for (int r = 0; r < 4; r++) {
    float mx = fmaxf(fmaxf(sv[0][r], sv[1][r]), fmaxf(sv[2][r], sv[3][r]));
#pragma unroll
    for (int off = 1; off < 16; off <<= 1) mx = fmaxf(mx, __shfl_xor(mx, off));
    float mn = fmaxf(m_r[r], mx);
    float rs = 0.0f;
#pragma unroll
    for (int c = 0; c < 4; c++) {
      float p = fexp2(sv[c][r] - mn);
      sv[c][r] = p;
      rs += p;
    }
#pragma unroll
    for (int off = 1; off < 16; off <<= 1) rs += __shfl_xor(rs, off);
    alpha[r] = fexp2(m_r[r] - mn);
    l_r[r] = l_r[r] * alpha[r] + rs;
    m_r[r] = mn;
  }
#pragma unroll
  for (int c = 0; c < 4; c++)
#pragma unroll
    for (int r = 0; r < 4; r++) oacc[c][r] *= alpha[r];
  // C-layout -> A-layout via per-wave LDS slice (padded to 72: conflict-free,
  // 144 B row stride keeps 16 B alignment)
#pragma unroll
  for (int c = 0; c < 4; c++)
#pragma unroll
    for (int r = 0; r < 4; r++)
      pl[quad * 4 + r][c * 16 + ml] = f2b(sv[c][r]);
  bf8 pf[2];
#pragma unroll
  for (int kk = 0; kk < 2; kk++) pf[kk] = ld8(&pl[ml][kk * 32 + quad * 8]);
  __builtin_amdgcn_s_setprio(1);
#pragma unroll
  for (int c = 0; c < 4; c++)
#pragma unroll
    for (int kk = 0; kk < 2; kk++) {
      int chunk = ((c * 16 + ml) << 3) + ((kk * 4 + quad) ^ (ml & 7));
      bf8 vf = ld8(&Vs[chunk * 8]);
      oacc[c] = MFMA(pf[kk], vf, oacc[c]);
    }
  __builtin_amdgcn_s_setprio(0);
}

__global__ __launch_bounds__(256) void flash_attn(const bf16* __restrict__ qkv,
                                                  const bf16* __restrict__ VT,
                                                  bf16* __restrict__ obuf) {
  // T1 XCD swizzle: 512 blocks, 8 XCDs, dispatch round-robins rb%8. Remap so
  // XCD x handles logical bids [x*64, x*64+64) = 4 complete (b,h) groups ->
  // that XCD's L2 holds their K/V (4 x 512KB = 2MB < 4MB). Bijective.
  int rb = blockIdx.x;
  int bid = (rb & 7) * 64 + (rb >> 3);
  // complementary blk pairing: adjacent logical blocks get workloads summing
  // to a constant 49 tiles (maxn(blk)=32-blk; pair j/2 with 15-j/2).
  int j = bid & 15;
  int blk = (j & 1) ? (15 - (j >> 1)) : (j >> 1);
  int h = (bid >> 4) & 15;
  int b = bid >> 8;
  int tid = threadIdx.x;
  int wv = tid >> 6, lane = tid & 63;
  int ml = lane & 15, quad = lane >> 4;
  int idx0 = blk * 4 + wv;              // phase-0 subtile (16 Q rows)
  int idx1 = 127 - idx0;                // phase-1 (antithetic)
  int q0a = idx0 * 16, q0b = idx1 * 16;
  int nkt0 = blk + 1;                   // block-uniform (idx0>>2 == blk)
  int nkt1 = 32 - blk;                  // block-uniform; nkt1 >= nkt0
  int maxn = nkt1;

  __shared__ __align__(16) bf16 Ks[2][64 * 64];
  __shared__ __align__(16) bf16 Vs[2][64 * 64];
  __shared__ __align__(16) bf16 plds[4][16][72];
  bf16 (*pl)[72] = plds[wv];

  bf8 qfa[2], qfb[2];
#pragma unroll
  for (int kk = 0; kk < 2; kk++) {
    qfa[kk] = ld8(qkv + (size_t)(b * SS + q0a + ml) * (3 * DDIM) + h * 64 + kk * 32 + quad * 8);
    qfb[kk] = ld8(qkv + (size_t)(b * SS + q0b + ml) * (3 * DDIM) + h * 64 + kk * 32 + quad * 8);
  }
  f4 oacca[4] = {{0,0,0,0},{0,0,0,0},{0,0,0,0},{0,0,0,0}};
  f4 oaccb[4] = {{0,0,0,0},{0,0,0,0},{0,0,0,0},{0,0,0,0}};
  float ma[4], la[4], mb[4], lb[4];
#pragma unroll
  for (int r = 0; r < 4; r++) {
    ma[r] = -1e30f; la[r] = 0.0f;
    mb[r] = -1e30f; lb[r] = 0.0f;
  }

  const bf16* kglob = qkv + (size_t)b * SS * (3 * DDIM) + DDIM + h * 64;
  const bf16* vglob = VT + (size_t)(b * NHEAD + h) * 64 * SS;

  // prologue: stage tile 0 into buffer 0 (swizzled SOURCE, lane-linear dest)
#pragma unroll
  for (int it = 0; it < 2; it++) {
    int lam = it * 256 + tid;
    int row = lam >> 3;
    int ch = (lam & 7) ^ (row & 7);
    glds16(&Ks[0][lam * 8], kglob + (size_t)row * (3 * DDIM) + ch * 8);
    glds16(&Vs[0][lam * 8], vglob + (size_t)row * SS + ch * 8);
  }
  __syncthreads();
  int cur = 0;
  for (int kt = 0; kt < maxn; kt++) {
    if (kt + 1 < maxn) {                // prefetch next K/V tile
      int k0n = (kt + 1) * 64;
#pragma unroll
      for (int it = 0; it < 2; it++) {
        int lam = it * 256 + tid;
        int row = lam >> 3;
        int ch = (lam & 7) ^ (row & 7);
        glds16(&Ks[cur ^ 1][lam * 8], kglob + (size_t)(k0n + row) * (3 * DDIM) + ch * 8);
        glds16(&Vs[cur ^ 1][lam * 8], vglob + (size_t)row * SS + k0n + ch * 8);
      }
    }
    phase_tile(kt, q0a, nkt0, qfa, oacca, ma, la, Ks[cur], Vs[cur], pl, ml, quad);
    phase_tile(kt, q0b, nkt1, qfb, oaccb, mb, lb, Ks[cur], Vs[cur], pl, ml, quad);
    __syncthreads();                    // vmcnt(0)+lgkmcnt(0)+barrier
    cur ^= 1;
  }
#pragma unroll
  for (int c = 0; c < 4; c++)
#pragma unroll
    for (int r = 0; r < 4; r++) {
      int rowa = q0a + quad * 4 + r;
      int rowb = q0b + quad * 4 + r;
      obuf[(size_t)(b * SS + rowa) * DDIM + h * 64 + c * 16 + ml] =
          f2b(oacca[c][r] / la[r]);
      obuf[(size_t)(b * SS + rowb) * DDIM + h * 64 + c * 16 + ml] =
          f2b(oaccb[c][r] / lb[r]);
    }
}

// ---------------- final: out = y + P0 + P1 + b2 + mhc(XD) ----------------
__global__ __launch_bounds__(256) void final_k(const float* __restrict__ y,
                                               const float* __restrict__ P0,
                                               const float* __restrict__ P1,
                                               const float* __restrict__ bias,
                                               const float* __restrict__ xd,
                                               const float* __restrict__ hres,
                                               const float* __restrict__ gres,
                                               float* __restrict__ out) {
  int row = blockIdx.x;  // [B*S]
  int b = row / SS;
  int tid = threadIdx.x;
  __shared__ float cf[8][8];
  if (tid < 64) cf[tid >> 3][tid & 7] = hres[tid] * gres[b * NSTR + (tid & 7)];
  __syncthreads();
  const float* yr = y + (size_t)row * DDIM;
  const float* p0 = P0 + (size_t)row * DDIM;
  const float* p1 = P1 + (size_t)row * DDIM;
  const float* xr = xd + (size_t)row * DDIM;
  float* o = out + (size_t)row * DDIM;
  for (int i = tid; i < DDIM; i += 256) {
    int m = i >> 7, dd = i & 127;
    float acc = yr[i] + p0[i] + p1[i] + bias[i];
#pragma unroll
    for (int n = 0; n < 8; n++) acc += cf[m][n] * xr[n * SDIMC + dd];
    o[i] = acc;
  }
}

extern "C" void kernel_launch(void* const* d_in, const int* in_sizes, int n_in,
                              void* d_out, int out_size, void* d_ws, size_t ws_size,
                              hipStream_t stream) {
  const float* x     = (const float*)d_in[0];
  const float* decay = (const float*)d_in[3];
  const float* gw    = (const float*)d_in[4];
  const float* gb    = (const float*)d_in[5];
  const float* phi   = (const float*)d_in[6];
  const float* ln1   = (const float*)d_in[7];
  const float* ln2   = (const float*)d_in[8];
  const float* w1    = (const float*)d_in[9];
  const float* b1    = (const float*)d_in[10];
  const float* w2    = (const float*)d_in[11];
  const float* b2    = (const float*)d_in[12];
  const float* ipw   = (const float*)d_in[13];
  const float* ipb   = (const float*)d_in[14];
  const float* ow    = (const float*)d_in[15];
  const float* obs   = (const float*)d_in[16];
  float* out = (float*)d_out;

  // ---- workspace layout (105 MB total) ----
  const size_t MB = 1048576ull;
  char* wsp = (char*)d_ws;
  float* SA   = (float*)(wsp);                 // 128 KB  chunk states / sums
  float* SIN  = (float*)(wsp + 131072ull);     // 128 KB  incoming states
  float* GRES = (float*)(wsp + 262144ull);     // 64 B
  float* HRES = (float*)(wsp + 262208ull);     // 256 B
  float* XD   = (float*)(wsp + 1 * MB);        // 16 MB   x_delta (f32), live to end
  float* AO   = (float*)(wsp + 17 * MB);       // 16 MB   y = x_delta + attn_out
  bf16*  NORM = (bf16*)(wsp + 33 * MB);        // 8 MB    normed/normed2 (dead after ffn1)
  bf16*  OB   = (bf16*)(wsp + 41 * MB);        // 8 MB    attn out (dead after outproj)
  bf16*  QKV  = (bf16*)(wsp + 49 * MB);        // 24 MB   (dead after flash)
  bf16*  VT   = (bf16*)(wsp + 73 * MB);        // 8 MB    (dead after flash)
  bf16*  HB   = (bf16*)(wsp + 49 * MB);        // 32 MB   gelu hidden, ALIASES QKV+VT
  bf16*  WIPW = (bf16*)(wsp + 81 * MB);        // 6 MB    in_proj_w bf16 (dead after qkv)
  bf16*  WOW  = (bf16*)(wsp + 87 * MB);        // 2 MB    out_w bf16 (dead after outproj)
  bf16*  W1B  = (bf16*)(wsp + 89 * MB);        // 8 MB    w1 bf16 (dead after ffn1)
  bf16*  W2B  = (bf16*)(wsp + 97 * MB);        // 8 MB    w2 bf16 (live thru ffn2)
  // ffn2 split-K partials (f32, 16 MB each), live from ffn2 thru final_k:
  // PK0 over NORM+OB (33-49 MB, dead), PK1 over WIPW/WOW/W1B (81-97 MB, dead)
  float* PK0  = (float*)(wsp + 33 * MB);
  float* PK1  = (float*)(wsp + 81 * MB);

  // 0: convert all GEMM weights f32 -> bf16 (single launch, float4 -> 8B pack)
  cvt_all<<<dim3(12 * DDIM * DDIM / 1024), dim3(256), 0, stream>>>(
      ipw, ow, w1, w2, WIPW, WOW, W1B, W2B);

  // 1-3: delta operator scan
  delta_passA<<<dim3(BB * NCH * DDIM / 256), dim3(256), 0, stream>>>(x, decay, SA);
  delta_passB<<<dim3(BB * DDIM / 256), dim3(256), 0, stream>>>(SA, decay, SIN);
  delta_passC<<<dim3(BB * NCH * DDIM / 256), dim3(256), 0, stream>>>(x, decay, SIN, XD, SA);
  // 4: gates + sinkhorn
  gates_sinkhorn<<<dim3(1), dim3(1024), 0, stream>>>(SA, gw, gb, phi, GRES, HRES);
  // 5: rmsnorm1 (XD -> NORM)
  rmsnorm_k<<<dim3(BB * SS), dim3(256), 0, stream>>>(XD, ln1, NORM);
  // 6: qkv = NORM @ in_proj_w.T + in_proj_b   [4096 x 3072]
  gemm_lds<1, 0><<<dim3(32, 24), dim3(256), 0, stream>>>(NORM, WIPW, ipb, nullptr,
                                                         QKV, BB * SS, 3 * DDIM, DDIM);
  // 7: V transpose
  vtrans<<<dim3(BB * NHEAD * (SS / 64)), dim3(256), 0, stream>>>(QKV, VT);
  // 8: flash attention -> OB (XCD-swizzled, double-buffered K/V, setprio)
  flash_attn<<<dim3(BB * NHEAD * 16), dim3(256), 0, stream>>>(QKV, VT, OB);
  // 9: out-proj + residual(XD) -> AO (= y)
  gemm_lds64<0, 2><<<dim3(64, 8), dim3(256), 0, stream>>>(OB, WOW, obs, XD,
                                                          AO, BB * SS, DDIM, DDIM);
  // 10: rmsnorm2 (AO -> NORM)
  rmsnorm_k<<<dim3(BB * SS), dim3(256), 0, stream>>>(AO, ln2, NORM);
  // 11: ffn1 + gelu -> HB   [4096 x 4096]  (HB aliases dead QKV/VT)
  gemm_lds<1, 1><<<dim3(32, 32), dim3(256), 0, stream>>>(NORM, W1B, b1, nullptr,
                                                         HB, BB * SS, 4 * DDIM, DDIM);
  // 12: ffn2 split-K=2, ONE launch (512 co-resident blocks) -> PK0/PK1
  gemm_part2<<<dim3(32, 8, 2), dim3(256), 0, stream>>>(HB, W2B, PK0, PK1,
                                                       BB * SS, DDIM, 2 * DDIM, 4 * DDIM);
  // 13: final out = y + PK0 + PK1 + b2 + mhc(XD)  (ffn2 epilogue fused here)
  final_k<<<dim3(BB * SS), dim3(256), 0, stream>>>(AO, PK0, PK1, b2, XD,
                                                   HRES, GRES, out);
}

// Round 3
// 425.634 us; speedup vs baseline: 1.1075x; 1.0421x over previous
//
#include <hip/hip_runtime.h>
#include <hip/hip_bf16.h>
#include <math.h>

// Problem constants
#define BB 2
#define SS 2048
#define DDIM 1024
#define NHEAD 16
#define NSTR 8
#define SDIMC 128
#define NCH 16      // chunks for delta scan
#define CLEN 128    // chunk length
#define EPSV 1e-6f

using bf16 = __hip_bfloat16;
typedef __attribute__((ext_vector_type(8))) __bf16 bf8;
typedef __attribute__((ext_vector_type(4))) __bf16 bf4v;
typedef __attribute__((ext_vector_type(4))) float f4;

__device__ __forceinline__ bf16 f2b(float v) { return __float2bfloat16(v); }
__device__ __forceinline__ bf8 ld8(const bf16* p) { return *(const bf8*)p; }
__device__ __forceinline__ f4 MFMA(bf8 a, bf8 b, f4 c) {
  return __builtin_amdgcn_mfma_f32_16x16x32_bf16(a, b, c, 0, 0, 0);
}
__device__ __forceinline__ float sigm(float x) { return 1.0f / (1.0f + expf(-x)); }
__device__ __forceinline__ float fexp2(float x) { return __builtin_amdgcn_exp2f(x); }

// fast gelu (exact-erf form) via Abramowitz-Stegun 7.1.26: |erf err| <= 1.5e-7,
// far below bf16 store rounding. hw rcp + hw exp2 instead of libm erff.
__device__ __forceinline__ float gelu_f(float v) {
  float x = v * 0.70710678118654752f;
  float ax = fabsf(x);
  float t = __builtin_amdgcn_rcpf(1.0f + 0.3275911f * ax);
  float p = ((((1.061405429f * t - 1.453152027f) * t + 1.421413741f) * t
              - 0.284496736f) * t + 0.254829592f) * t;
  float e = 1.0f - p * fexp2(-ax * ax * 1.4426950408889634f);
  e = copysignf(e, x);
  return 0.5f * v * (1.0f + e);
}

// async global->LDS 16B copy (m97 pattern; LDS dest must be uniform + lane*16)
__device__ __forceinline__ void glds16(bf16* l, const bf16* g) {
  __builtin_amdgcn_global_load_lds(
      (const __attribute__((address_space(1))) unsigned int*)g,
      (__attribute__((address_space(3))) unsigned int*)l, 16, 0, 0);
}

// ---------------- f32 -> bf16 weight conversion (all 4 weights, one launch) --
__global__ __launch_bounds__(256) void cvt_all(const float* __restrict__ ipw,
                                               const float* __restrict__ ow,
                                               const float* __restrict__ w1,
                                               const float* __restrict__ w2,
                                               bf16* __restrict__ WIPW,
                                               bf16* __restrict__ WOW,
                                               bf16* __restrict__ W1B,
                                               bf16* __restrict__ W2B) {
  const int S1 = 3 * DDIM * DDIM, S2 = S1 + DDIM * DDIM,
            S3 = S2 + 4 * DDIM * DDIM;
  int i4 = (blockIdx.x * 256 + threadIdx.x) * 4;   // grid covers 12.58M elems
  const float* src;
  bf16* dst;
  int off;
  if (i4 < S1)      { src = ipw; dst = WIPW; off = i4; }
  else if (i4 < S2) { src = ow;  dst = WOW;  off = i4 - S1; }
  else if (i4 < S3) { src = w1;  dst = W1B;  off = i4 - S2; }
  else              { src = w2;  dst = W2B;  off = i4 - S3; }
  float4 v = *(const float4*)(src + off);
  bf4v o;
  o[0] = (__bf16)v.x; o[1] = (__bf16)v.y; o[2] = (__bf16)v.z; o[3] = (__bf16)v.w;
  *(bf4v*)(dst + off) = o;                         // one 8B store, fully packed
}

// ---------------- Delta operator: 3-pass chunked affine scan ----------------
__global__ __launch_bounds__(256) void delta_passA(const float* __restrict__ x,
                                                   const float* __restrict__ decay,
                                                   float* __restrict__ SA) {
  int idx = blockIdx.x * 256 + threadIdx.x;      // [b][c][d]
  int d = idx % DDIM;
  int c = (idx / DDIM) % NCH;
  int b = idx / (DDIM * NCH);
  float beta = sigm(decay[d]);
  float omb = 1.0f - beta;
  const float* xp = x + ((size_t)(b * SS + c * CLEN)) * DDIM + d;
  float s = 0.0f;
  for (int j = 0; j < CLEN; j++) {
    float xv = xp[(size_t)j * DDIM];
    s = beta * s + omb * xv;
  }
  SA[idx] = s;
}

__global__ __launch_bounds__(256) void delta_passB(const float* __restrict__ SA,
                                                   const float* __restrict__ decay,
                                                   float* __restrict__ SIN) {
  int idx = blockIdx.x * 256 + threadIdx.x;      // [b][d]
  int d = idx % DDIM;
  int b = idx / DDIM;
  float beta = sigm(decay[d]);
  float p = beta;
  for (int i = 0; i < 7; i++) p *= p;            // beta^128
  float s = 0.0f;
  for (int c = 0; c < NCH; c++) {
    SIN[(b * NCH + c) * DDIM + d] = s;
    s = p * s + SA[(b * NCH + c) * DDIM + d];
  }
}

__global__ __launch_bounds__(256) void delta_passC(const float* __restrict__ x,
                                                   const float* __restrict__ decay,
                                                   const float* __restrict__ SIN,
                                                   float* __restrict__ XD,
                                                   float* __restrict__ SA) {
  int idx = blockIdx.x * 256 + threadIdx.x;      // [b][c][d]
  int d = idx % DDIM;
  int c = (idx / DDIM) % NCH;
  int b = idx / (DDIM * NCH);
  float beta = sigm(decay[d]);
  float omb = 1.0f - beta;
  const float* xp = x + ((size_t)(b * SS + c * CLEN)) * DDIM + d;
  float* xdp = XD + ((size_t)(b * SS + c * CLEN)) * DDIM + d;
  float s = SIN[idx];
  float sum = 0.0f;
  for (int j = 0; j < CLEN; j++) {
    float xv = xp[(size_t)j * DDIM];
    float o = xv - s;
    xdp[(size_t)j * DDIM] = o;
    sum += o;
    s = beta * s + omb * xv;
  }
  SA[idx] = sum;
}

// ---------------- gates (g_res) + sinkhorn ----------------
__global__ __launch_bounds__(1024) void gates_sinkhorn(const float* __restrict__ SA,
                                                       const float* __restrict__ gw,
                                                       const float* __restrict__ gb,
                                                       const float* __restrict__ phi,
                                                       float* __restrict__ gres,
                                                       float* __restrict__ hres) {
  int tid = threadIdx.x;
  int wave = tid >> 6, lane = tid & 63;
  int b = wave >> 3, j = wave & 7;               // 16 waves: (b, gate j)
  float acc = 0.0f;
  for (int d = lane; d < DDIM; d += 64) {
    float xs = 0.0f;
    for (int c = 0; c < NCH; c++) xs += SA[(b * NCH + c) * DDIM + d];
    xs *= (1.0f / (float)SS);
    acc += xs * gw[(2 * NSTR + j) * DDIM + d];
  }
  for (int off = 32; off > 0; off >>= 1) acc += __shfl_down(acc, off);
  if (lane == 0) gres[b * NSTR + j] = sigm(acc + gb[2 * NSTR + j]);
  __syncthreads();
  if (tid == 0) {
    float Km[8][8];
    for (int i = 0; i < 8; i++)
      for (int jj = 0; jj < 8; jj++) Km[i][jj] = expf(phi[i * 8 + jj]);
    for (int it = 0; it < 15; it++) {
      for (int i = 0; i < 8; i++) {
        float rs = 0.0f;
        for (int jj = 0; jj < 8; jj++) rs += Km[i][jj];
        float inv = 1.0f / rs;
        for (int jj = 0; jj < 8; jj++) Km[i][jj] *= inv;
      }
      for (int jj = 0; jj < 8; jj++) {
        float cs = 0.0f;
        for (int i = 0; i < 8; i++) cs += Km[i][jj];
        float inv = 1.0f / cs;
        for (int i = 0; i < 8; i++) Km[i][jj] *= inv;
      }
    }
    for (int i = 0; i < 8; i++)
      for (int jj = 0; jj < 8; jj++) hres[i * 8 + jj] = Km[i][jj];
  }
}

// ---------------- RMSNorm (f32 in -> bf16 out) ----------------
__global__ __launch_bounds__(256) void rmsnorm_k(const float* __restrict__ in,
                                                 const float* __restrict__ w,
                                                 bf16* __restrict__ out) {
  int row = blockIdx.x;
  const float* r = in + (size_t)row * DDIM;
  int tid = threadIdx.x;
  float ss = 0.0f;
  for (int i = tid; i < DDIM; i += 256) {
    float v = r[i];
    ss += v * v;
  }
  for (int off = 32; off > 0; off >>= 1) ss += __shfl_down(ss, off);
  __shared__ float red[4];
  if ((tid & 63) == 0) red[tid >> 6] = ss;
  __syncthreads();
  float tot = red[0] + red[1] + red[2] + red[3];
  float sc = rsqrtf(tot / (float)DDIM + EPSV);
  bf16* o = out + (size_t)row * DDIM;
  for (int i = tid; i < DDIM; i += 256) o[i] = f2b(r[i] * sc * w[i]);
}

// ------- MFMA GEMM, 128x128 tile, BK=32, DOUBLE-BUFFERED single-barrier loop.
// T3-minimal recipe: issue next tile's global_load_lds BEFORE ds_read+MFMA of
// current tile; one __syncthreads (vmcnt(0)+lgkmcnt(0)+barrier) per K-step.
// ODT: 0=f32 out, 1=bf16 out.  EPI: 0=none, 1=gelu(exact erf), 2=add residual
template <int ODT, int EPI>
__global__ __launch_bounds__(256) void gemm_lds(const bf16* __restrict__ A,
                                                const bf16* __restrict__ W,
                                                const float* __restrict__ bias,
                                                const float* __restrict__ res,
                                                void* __restrict__ outp,
                                                int M, int N, int K) {
  __shared__ bf16 As[2][128 * 32];
  __shared__ bf16 Bs[2][128 * 32];
  int tid = threadIdx.x;
  int lane = tid & 63, wv = tid >> 6;
  int ml = lane & 15, quad = lane >> 4;
  int wr = wv >> 1, wc = wv & 1;
  int m0 = blockIdx.x * 128, n0 = blockIdx.y * 128;
  // per-thread staging addresses (2 chunks each of A,B)
  const bf16* ga[2];
  const bf16* gb[2];
  int lofs[2];
#pragma unroll
  for (int it = 0; it < 2; it++) {
    int c = it * 256 + tid;             // 512 16B-chunks per tile
    int row = c >> 2, kc = (c & 3) * 8;
    ga[it] = A + (size_t)(m0 + row) * K + kc;
    gb[it] = W + (size_t)(n0 + row) * K + kc;
    lofs[it] = c * 8;
  }
  // prologue: stage tile 0 into buffer 0
#pragma unroll
  for (int it = 0; it < 2; it++) {
    glds16(&As[0][lofs[it]], ga[it]);
    glds16(&Bs[0][lofs[it]], gb[it]);
  }
  f4 acc[4][4] = {};
  int nk = K >> 5;
  int cur = 0;
  __syncthreads();
  for (int t = 0; t < nk; t++) {
    if (t + 1 < nk) {                    // prefetch tile t+1 into other buffer
      int ko = (t + 1) * 32;
#pragma unroll
      for (int it = 0; it < 2; it++) {
        glds16(&As[cur ^ 1][lofs[it]], ga[it] + ko);
        glds16(&Bs[cur ^ 1][lofs[it]], gb[it] + ko);
      }
    }
    bf8 af[4], bfr[4];
#pragma unroll
    for (int mi = 0; mi < 4; mi++)
      af[mi] = ld8(&As[cur][(wr * 64 + mi * 16 + ml) * 32 + quad * 8]);
#pragma unroll
    for (int ni = 0; ni < 4; ni++)
      bfr[ni] = ld8(&Bs[cur][(wc * 64 + ni * 16 + ml) * 32 + quad * 8]);
#pragma unroll
    for (int mi = 0; mi < 4; mi++)
#pragma unroll
      for (int ni = 0; ni < 4; ni++)
        acc[mi][ni] = MFMA(af[mi], bfr[ni], acc[mi][ni]);
    __syncthreads();                     // vmcnt(0)+lgkmcnt(0)+barrier
    cur ^= 1;
  }
#pragma unroll
  for (int mi = 0; mi < 4; mi++)
#pragma unroll
    for (int ni = 0; ni < 4; ni++)
#pragma unroll
      for (int r = 0; r < 4; r++) {
        int row = m0 + wr * 64 + mi * 16 + quad * 4 + r;
        int col = n0 + wc * 64 + ni * 16 + ml;
        size_t idx = (size_t)row * N + col;
        float v = acc[mi][ni][r] + bias[col];
        if (EPI == 1) v = gelu_f(v);
        if (EPI == 2) v += res[idx];
        if (ODT == 1) ((bf16*)outp)[idx] = f2b(v);
        else ((float*)outp)[idx] = v;
      }
}

// ------- ffn2 split-K=2, ONE launch, grid (32,8,2): z picks K-slice+buffer ---
// same double-buffered single-barrier structure
__global__ __launch_bounds__(256) void gemm_part2(const bf16* __restrict__ A,
                                                  const bf16* __restrict__ W,
                                                  float* __restrict__ P0,
                                                  float* __restrict__ P1,
                                                  int M, int N, int KS, int LDK) {
  __shared__ bf16 As[2][128 * 32];
  __shared__ bf16 Bs[2][128 * 32];
  int tid = threadIdx.x;
  int lane = tid & 63, wv = tid >> 6;
  int ml = lane & 15, quad = lane >> 4;
  int wr = wv >> 1, wc = wv & 1;
  int m0 = blockIdx.x * 128, n0 = blockIdx.y * 128;
  const bf16* Ab = A + blockIdx.z * KS;
  const bf16* Wb = W + blockIdx.z * KS;
  float* P = blockIdx.z ? P1 : P0;
  const bf16* ga[2];
  const bf16* gb[2];
  int lofs[2];
#pragma unroll
  for (int it = 0; it < 2; it++) {
    int c = it * 256 + tid;
    int row = c >> 2, kc = (c & 3) * 8;
    ga[it] = Ab + (size_t)(m0 + row) * LDK + kc;
    gb[it] = Wb + (size_t)(n0 + row) * LDK + kc;
    lofs[it] = c * 8;
  }
#pragma unroll
  for (int it = 0; it < 2; it++) {
    glds16(&As[0][lofs[it]], ga[it]);
    glds16(&Bs[0][lofs[it]], gb[it]);
  }
  f4 acc[4][4] = {};
  int nk = KS >> 5;
  int cur = 0;
  __syncthreads();
  for (int t = 0; t < nk; t++) {
    if (t + 1 < nk) {
      int ko = (t + 1) * 32;
#pragma unroll
      for (int it = 0; it < 2; it++) {
        glds16(&As[cur ^ 1][lofs[it]], ga[it] + ko);
        glds16(&Bs[cur ^ 1][lofs[it]], gb[it] + ko);
      }
    }
    bf8 af[4], bfr[4];
#pragma unroll
    for (int mi = 0; mi < 4; mi++)
      af[mi] = ld8(&As[cur][(wr * 64 + mi * 16 + ml) * 32 + quad * 8]);
#pragma unroll
    for (int ni = 0; ni < 4; ni++)
      bfr[ni] = ld8(&Bs[cur][(wc * 64 + ni * 16 + ml) * 32 + quad * 8]);
#pragma unroll
    for (int mi = 0; mi < 4; mi++)
#pragma unroll
      for (int ni = 0; ni < 4; ni++)
        acc[mi][ni] = MFMA(af[mi], bfr[ni], acc[mi][ni]);
    __syncthreads();
    cur ^= 1;
  }
#pragma unroll
  for (int mi = 0; mi < 4; mi++)
#pragma unroll
    for (int ni = 0; ni < 4; ni++)
#pragma unroll
      for (int r = 0; r < 4; r++) {
        int row = m0 + wr * 64 + mi * 16 + quad * 4 + r;
        int col = n0 + wc * 64 + ni * 16 + ml;
        P[(size_t)row * N + col] = acc[mi][ni][r];
      }
}

// ------- MFMA GEMM, BM=64 x BN=128 variant, double-buffered ---------------
template <int ODT, int EPI>
__global__ __launch_bounds__(256) void gemm_lds64(const bf16* __restrict__ A,
                                                  const bf16* __restrict__ W,
                                                  const float* __restrict__ bias,
                                                  const float* __restrict__ res,
                                                  void* __restrict__ outp,
                                                  int M, int N, int K) {
  __shared__ bf16 As[2][64 * 32];
  __shared__ bf16 Bs[2][128 * 32];
  int tid = threadIdx.x;
  int lane = tid & 63, wv = tid >> 6;
  int ml = lane & 15, quad = lane >> 4;
  int wr = wv & 1, wc = wv >> 1;        // wave tile: 32 rows x 64 cols
  int m0 = blockIdx.x * 64, n0 = blockIdx.y * 128;
  const bf16* gaA;
  const bf16* gb[2];
  int lofA, lofs[2];
  {
    int c = tid;                        // A: 256 chunks
    int row = c >> 2, kc = (c & 3) * 8;
    gaA = A + (size_t)(m0 + row) * K + kc;
    lofA = c * 8;
  }
#pragma unroll
  for (int it = 0; it < 2; it++) {      // B: 512 chunks
    int c = it * 256 + tid;
    int row = c >> 2, kc = (c & 3) * 8;
    gb[it] = W + (size_t)(n0 + row) * K + kc;
    lofs[it] = c * 8;
  }
  glds16(&As[0][lofA], gaA);
#pragma unroll
  for (int it = 0; it < 2; it++) glds16(&Bs[0][lofs[it]], gb[it]);
  f4 acc[2][4] = {};
  int nk = K >> 5;
  int cur = 0;
  __syncthreads();
  for (int t = 0; t < nk; t++) {
    if (t + 1 < nk) {
      int ko = (t + 1) * 32;
      glds16(&As[cur ^ 1][lofA], gaA + ko);
#pragma unroll
      for (int it = 0; it < 2; it++) glds16(&Bs[cur ^ 1][lofs[it]], gb[it] + ko);
    }
    bf8 af[2], bfr[4];
#pragma unroll
    for (int mi = 0; mi < 2; mi++)
      af[mi] = ld8(&As[cur][(wr * 32 + mi * 16 + ml) * 32 + quad * 8]);
#pragma unroll
    for (int ni = 0; ni < 4; ni++)
      bfr[ni] = ld8(&Bs[cur][(wc * 64 + ni * 16 + ml) * 32 + quad * 8]);
#pragma unroll
    for (int mi = 0; mi < 2; mi++)
#pragma unroll
      for (int ni = 0; ni < 4; ni++)
        acc[mi][ni] = MFMA(af[mi], bfr[ni], acc[mi][ni]);
    __syncthreads();
    cur ^= 1;
  }
#pragma unroll
  for (int mi = 0; mi < 2; mi++)
#pragma unroll
    for (int ni = 0; ni < 4; ni++)
#pragma unroll
      for (int r = 0; r < 4; r++) {
        int row = m0 + wr * 32 + mi * 16 + quad * 4 + r;
        int col = n0 + wc * 64 + ni * 16 + ml;
        size_t idx = (size_t)row * N + col;
        float v = acc[mi][ni][r] + bias[col];
        if (EPI == 1) v = gelu_f(v);
        if (EPI == 2) v += res[idx];
        if (ODT == 1) ((bf16*)outp)[idx] = f2b(v);
        else ((float*)outp)[idx] = v;
      }
}

// ---------------- V transpose: VT[b,h,d,s] = qkv[b,s,2D + h*64 + d] --------
__global__ __launch_bounds__(256) void vtrans(const bf16* __restrict__ qkv,
                                              bf16* __restrict__ VT) {
  int bid = blockIdx.x;
  int st = bid % (SS / 64);
  int h = (bid / (SS / 64)) % NHEAD;
  int b = bid / ((SS / 64) * NHEAD);
  __shared__ bf16 tile[64][65];
  int s0 = st * 64;
  int tid = threadIdx.x;
  for (int it = 0; it < 16; it++) {
    int sl = it * 4 + (tid >> 6), dl = tid & 63;
    tile[sl][dl] = qkv[(size_t)(b * SS + s0 + sl) * (3 * DDIM) + 2 * DDIM + h * 64 + dl];
  }
  __syncthreads();
  for (int it = 0; it < 16; it++) {
    int dl = it * 4 + (tid >> 6), sl = tid & 63;
    VT[((size_t)(b * NHEAD + h) * 64 + dl) * SS + s0 + sl] = tile[sl][dl];
  }
}

// ---- Flash attention v10: SWAPPED QK^T (mfma(K,Q) -> S^T, lane owns one
// q-row) -> in-lane softmax: 8 shuffles/phase (was 32), packed b64 P-writes
// (was 16 scalar), K/V fragments loaded ONCE per tile shared by both
// antithetic phases. Same fragment loads serve as A resp. B operands.
// C-layout of swapped QK^T: q = ml, k = k0 + c*16 + quad*4 + r.
// O-layout (PV unchanged): q = q0 + quad*4 + r, d = c*16 + ml -> alpha/l
// redistributed via 4 shuffles (lane quad*4+r holds q-row quad*4+r's state).
__device__ __forceinline__ void qk_softmax(bool active, int kt, int q0, int nkt,
                                           const bf8 kf[4][2], const bf8* qf,
                                           f4* oacc, float& m, float& l,
                                           bf8* pf, bf16 (*pl)[72],
                                           int ml, int quad, int k0) {
  if (!active) return;                   // block-uniform condition
  const float SC = 0.125f * 1.44269504089f;  // 1/sqrt(64) * log2(e)
  f4 s[4] = {{0,0,0,0},{0,0,0,0},{0,0,0,0},{0,0,0,0}};
  __builtin_amdgcn_s_setprio(1);
#pragma unroll
  for (int kk = 0; kk < 2; kk++)
#pragma unroll
    for (int c = 0; c < 4; c++)
      s[c] = MFMA(kf[c][kk], qf[kk], s[c]);   // S^T = K . Q^T
  __builtin_amdgcn_s_setprio(0);
  if (kt == nkt - 1) {                   // diagonal tile: causal mask
    int qi = q0 + ml;
#pragma unroll
    for (int c = 0; c < 4; c++)
#pragma unroll
      for (int r = 0; r < 4; r++)
        if (k0 + c * 16 + quad * 4 + r > qi) s[c][r] = -1e30f;
  }
  // in-lane max over 16 k-values, then 2-step quad reduce
  float mx = s[0][0];
#pragma unroll
  for (int c = 0; c < 4; c++)
#pragma unroll
    for (int r = 0; r < 4; r++) mx = fmaxf(mx, s[c][r]);
  mx = fmaxf(mx, __shfl_xor(mx, 16));
  mx = fmaxf(mx, __shfl_xor(mx, 32));
  float mn = fmaxf(m, mx * SC);
  float alpha = fexp2(m - mn);
  float rs = 0.0f;
  float p[4][4];
#pragma unroll
  for (int c = 0; c < 4; c++)
#pragma unroll
    for (int r = 0; r < 4; r++) {
      p[c][r] = fexp2(__builtin_fmaf(s[c][r], SC, -mn));
      rs += p[c][r];
    }
  rs += __shfl_xor(rs, 16);
  rs += __shfl_xor(rs, 32);
  l = l * alpha + rs;
  m = mn;
  // redistribute alpha (state row q=ml) to O-layout rows (q=quad*4+r):
  // source lane quad*4+r (lanes 0..15) holds q-row quad*4+r's alpha
  float alr[4];
#pragma unroll
  for (int r = 0; r < 4; r++) alr[r] = __shfl(alpha, quad * 4 + r);
#pragma unroll
  for (int c = 0; c < 4; c++)
#pragma unroll
    for (int r = 0; r < 4; r++) oacc[c][r] *= alr[r];
  // P is lane-local: pack 4 bf16 per chunk, one b64 write each (2-way banks)
#pragma unroll
  for (int c = 0; c < 4; c++) {
    bf4v w;
#pragma unroll
    for (int r = 0; r < 4; r++) w[r] = (__bf16)p[c][r];
    *(bf4v*)&pl[ml][c * 16 + quad * 4] = w;
  }
#pragma unroll
  for (int kk = 0; kk < 2; kk++) pf[kk] = ld8(&pl[ml][kk * 32 + quad * 8]);
}

__device__ __forceinline__ void pv_acc(bool active, const bf8* pf,
                                       const bf8 vf[4][2], f4* oacc) {
  if (!active) return;
  __builtin_amdgcn_s_setprio(1);
#pragma unroll
  for (int c = 0; c < 4; c++)
#pragma unroll
    for (int kk = 0; kk < 2; kk++)
      oacc[c] = MFMA(pf[kk], vf[c][kk], oacc[c]);
  __builtin_amdgcn_s_setprio(0);
}

__global__ __launch_bounds__(256) void flash_attn(const bf16* __restrict__ qkv,
                                                  const bf16* __restrict__ VT,
                                                  bf16* __restrict__ obuf) {
  // T1 XCD swizzle: 512 blocks, 8 XCDs, dispatch round-robins rb%8. Remap so
  // XCD x handles logical bids [x*64, x*64+64) = 4 complete (b,h) groups ->
  // that XCD's L2 holds their K/V (4 x 512KB = 2MB < 4MB). Bijective.
  int rb = blockIdx.x;
  int bid = (rb & 7) * 64 + (rb >> 3);
  // complementary blk pairing: adjacent logical blocks get workloads summing
  // to a constant 49 tiles (maxn(blk)=32-blk; pair j/2 with 15-j/2).
  int j = bid & 15;
  int blk = (j & 1) ? (15 - (j >> 1)) : (j >> 1);
  int h = (bid >> 4) & 15;
  int b = bid >> 8;
  int tid = threadIdx.x;
  int wv = tid >> 6, lane = tid & 63;
  int ml = lane & 15, quad = lane >> 4;
  int idx0 = blk * 4 + wv;              // phase-0 subtile (16 Q rows)
  int idx1 = 127 - idx0;                // phase-1 (antithetic)
  int q0a = idx0 * 16, q0b = idx1 * 16;
  int nkt0 = blk + 1;                   // block-uniform (idx0>>2 == blk)
  int nkt1 = 32 - blk;                  // block-uniform; nkt1 >= nkt0
  int maxn = nkt1;

  __shared__ __align__(16) bf16 Ks[2][64 * 64];
  __shared__ __align__(16) bf16 Vs[2][64 * 64];
  __shared__ __align__(16) bf16 plds[4][2][16][72];  // per-wave, per-phase
  bf16 (*plA)[72] = plds[wv][0];
  bf16 (*plB)[72] = plds[wv][1];

  bf8 qfa[2], qfb[2];
#pragma unroll
  for (int kk = 0; kk < 2; kk++) {
    qfa[kk] = ld8(qkv + (size_t)(b * SS + q0a + ml) * (3 * DDIM) + h * 64 + kk * 32 + quad * 8);
    qfb[kk] = ld8(qkv + (size_t)(b * SS + q0b + ml) * (3 * DDIM) + h * 64 + kk * 32 + quad * 8);
  }
  f4 oacca[4] = {{0,0,0,0},{0,0,0,0},{0,0,0,0},{0,0,0,0}};
  f4 oaccb[4] = {{0,0,0,0},{0,0,0,0},{0,0,0,0},{0,0,0,0}};
  float ma = -1e30f, la = 0.0f, mb = -1e30f, lb = 0.0f;

  const bf16* kglob = qkv + (size_t)b * SS * (3 * DDIM) + DDIM + h * 64;
  const bf16* vglob = VT + (size_t)(b * NHEAD + h) * 64 * SS;

  // prologue: stage tile 0 into buffer 0 (swizzled SOURCE, lane-linear dest)
#pragma unroll
  for (int it = 0; it < 2; it++) {
    int lam = it * 256 + tid;
    int row = lam >> 3;
    int ch = (lam & 7) ^ (row & 7);
    glds16(&Ks[0][lam * 8], kglob + (size_t)row * (3 * DDIM) + ch * 8);
    glds16(&Vs[0][lam * 8], vglob + (size_t)row * SS + ch * 8);
  }
  __syncthreads();
  int cur = 0;
  for (int kt = 0; kt < maxn; kt++) {
    int k0 = kt * 64;
    if (kt + 1 < maxn) {                // prefetch next K/V tile
      int k0n = (kt + 1) * 64;
#pragma unroll
      for (int it = 0; it < 2; it++) {
        int lam = it * 256 + tid;
        int row = lam >> 3;
        int ch = (lam & 7) ^ (row & 7);
        glds16(&Ks[cur ^ 1][lam * 8], kglob + (size_t)(k0n + row) * (3 * DDIM) + ch * 8);
        glds16(&Vs[cur ^ 1][lam * 8], vglob + (size_t)row * SS + k0n + ch * 8);
      }
    }
    bool act0 = kt < nkt0;              // block-uniform
    // K fragments: loaded once, shared by both phases (same ld8 serves as
    // MFMA A operand in swapped QK^T)
    bf8 kf[4][2];
#pragma unroll
    for (int kk = 0; kk < 2; kk++)
#pragma unroll
      for (int c = 0; c < 4; c++) {
        int chunk = ((c * 16 + ml) << 3) + ((kk * 4 + quad) ^ (ml & 7));
        kf[c][kk] = ld8(&Ks[cur][chunk * 8]);
      }
    bf8 pfa[2], pfb[2];
    qk_softmax(act0, kt, q0a, nkt0, kf, qfa, oacca, ma, la, pfa, plA, ml, quad, k0);
    qk_softmax(true, kt, q0b, nkt1, kf, qfb, oaccb, mb, lb, pfb, plB, ml, quad, k0);
    // V fragments: loaded once, shared by both phases
    bf8 vf[4][2];
#pragma unroll
    for (int kk = 0; kk < 2; kk++)
#pragma unroll
      for (int c = 0; c < 4; c++) {
        int chunk = ((c * 16 + ml) << 3) + ((kk * 4 + quad) ^ (ml & 7));
        vf[c][kk] = ld8(&Vs[cur][chunk * 8]);
      }
    pv_acc(act0, pfa, vf, oacca);
    pv_acc(true, pfb, vf, oaccb);
    __syncthreads();                    // vmcnt(0)+lgkmcnt(0)+barrier
    cur ^= 1;
  }
  // redistribute l (state row q=ml) to O-layout rows, then store
  float lna[4], lnb[4];
#pragma unroll
  for (int r = 0; r < 4; r++) {
    lna[r] = __shfl(la, quad * 4 + r);
    lnb[r] = __shfl(lb, quad * 4 + r);
  }
#pragma unroll
  for (int c = 0; c < 4; c++)
#pragma unroll
    for (int r = 0; r < 4; r++) {
      int rowa = q0a + quad * 4 + r;
      int rowb = q0b + quad * 4 + r;
      obuf[(size_t)(b * SS + rowa) * DDIM + h * 64 + c * 16 + ml] =
          f2b(oacca[c][r] / lna[r]);
      obuf[(size_t)(b * SS + rowb) * DDIM + h * 64 + c * 16 + ml] =
          f2b(oaccb[c][r] / lnb[r]);
    }
}

// ---------------- final: out = y + P0 + P1 + b2 + mhc(XD) ----------------
__global__ __launch_bounds__(256) void final_k(const float* __restrict__ y,
                                               const float* __restrict__ P0,
                                               const float* __restrict__ P1,
                                               const float* __restrict__ bias,
                                               const float* __restrict__ xd,
                                               const float* __restrict__ hres,
                                               const float* __restrict__ gres,
                                               float* __restrict__ out) {
  int row = blockIdx.x;  // [B*S]
  int b = row / SS;
  int tid = threadIdx.x;
  __shared__ float cf[8][8];
  if (tid < 64) cf[tid >> 3][tid & 7] = hres[tid] * gres[b * NSTR + (tid & 7)];
  __syncthreads();
  const float* yr = y + (size_t)row * DDIM;
  const float* p0 = P0 + (size_t)row * DDIM;
  const float* p1 = P1 + (size_t)row * DDIM;
  const float* xr = xd + (size_t)row * DDIM;
  float* o = out + (size_t)row * DDIM;
  for (int i = tid; i < DDIM; i += 256) {
    int m = i >> 7, dd = i & 127;
    float acc = yr[i] + p0[i] + p1[i] + bias[i];
#pragma unroll
    for (int n = 0; n < 8; n++) acc += cf[m][n] * xr[n * SDIMC + dd];
    o[i] = acc;
  }
}

extern "C" void kernel_launch(void* const* d_in, const int* in_sizes, int n_in,
                              void* d_out, int out_size, void* d_ws, size_t ws_size,
                              hipStream_t stream) {
  const float* x     = (const float*)d_in[0];
  const float* decay = (const float*)d_in[3];
  const float* gw    = (const float*)d_in[4];
  const float* gb    = (const float*)d_in[5];
  const float* phi   = (const float*)d_in[6];
  const float* ln1   = (const float*)d_in[7];
  const float* ln2   = (const float*)d_in[8];
  const float* w1    = (const float*)d_in[9];
  const float* b1    = (const float*)d_in[10];
  const float* w2    = (const float*)d_in[11];
  const float* b2    = (const float*)d_in[12];
  const float* ipw   = (const float*)d_in[13];
  const float* ipb   = (const float*)d_in[14];
  const float* ow    = (const float*)d_in[15];
  const float* obs   = (const float*)d_in[16];
  float* out = (float*)d_out;

  // ---- workspace layout (105 MB total) ----
  const size_t MB = 1048576ull;
  char* wsp = (char*)d_ws;
  float* SA   = (float*)(wsp);                 // 128 KB  chunk states / sums
  float* SIN  = (float*)(wsp + 131072ull);     // 128 KB  incoming states
  float* GRES = (float*)(wsp + 262144ull);     // 64 B
  float* HRES = (float*)(wsp + 262208ull);     // 256 B
  float* XD   = (float*)(wsp + 1 * MB);        // 16 MB   x_delta (f32), live to end
  float* AO   = (float*)(wsp + 17 * MB);       // 16 MB   y = x_delta + attn_out
  bf16*  NORM = (bf16*)(wsp + 33 * MB);        // 8 MB    normed/normed2 (dead after ffn1)
  bf16*  OB   = (bf16*)(wsp + 41 * MB);        // 8 MB    attn out (dead after outproj)
  bf16*  QKV  = (bf16*)(wsp + 49 * MB);        // 24 MB   (dead after flash)
  bf16*  VT   = (bf16*)(wsp + 73 * MB);        // 8 MB    (dead after flash)
  bf16*  HB   = (bf16*)(wsp + 49 * MB);        // 32 MB   gelu hidden, ALIASES QKV+VT
  bf16*  WIPW = (bf16*)(wsp + 81 * MB);        // 6 MB    in_proj_w bf16 (dead after qkv)
  bf16*  WOW  = (bf16*)(wsp + 87 * MB);        // 2 MB    out_w bf16 (dead after outproj)
  bf16*  W1B  = (bf16*)(wsp + 89 * MB);        // 8 MB    w1 bf16 (dead after ffn1)
  bf16*  W2B  = (bf16*)(wsp + 97 * MB);        // 8 MB    w2 bf16 (live thru ffn2)
  // ffn2 split-K partials (f32, 16 MB each), live from ffn2 thru final_k:
  // PK0 over NORM+OB (33-49 MB, dead), PK1 over WIPW/WOW/W1B (81-97 MB, dead)
  float* PK0  = (float*)(wsp + 33 * MB);
  float* PK1  = (float*)(wsp + 81 * MB);

  // 0: convert all GEMM weights f32 -> bf16 (single launch, float4 -> 8B pack)
  cvt_all<<<dim3(12 * DDIM * DDIM / 1024), dim3(256), 0, stream>>>(
      ipw, ow, w1, w2, WIPW, WOW, W1B, W2B);

  // 1-3: delta operator scan
  delta_passA<<<dim3(BB * NCH * DDIM / 256), dim3(256), 0, stream>>>(x, decay, SA);
  delta_passB<<<dim3(BB * DDIM / 256), dim3(256), 0, stream>>>(SA, decay, SIN);
  delta_passC<<<dim3(BB * NCH * DDIM / 256), dim3(256), 0, stream>>>(x, decay, SIN, XD, SA);
  // 4: gates + sinkhorn
  gates_sinkhorn<<<dim3(1), dim3(1024), 0, stream>>>(SA, gw, gb, phi, GRES, HRES);
  // 5: rmsnorm1 (XD -> NORM)
  rmsnorm_k<<<dim3(BB * SS), dim3(256), 0, stream>>>(XD, ln1, NORM);
  // 6: qkv = NORM @ in_proj_w.T + in_proj_b   [4096 x 3072]
  gemm_lds<1, 0><<<dim3(32, 24), dim3(256), 0, stream>>>(NORM, WIPW, ipb, nullptr,
                                                         QKV, BB * SS, 3 * DDIM, DDIM);
  // 7: V transpose
  vtrans<<<dim3(BB * NHEAD * (SS / 64)), dim3(256), 0, stream>>>(QKV, VT);
  // 8: flash attention -> OB (swapped QK^T, in-lane softmax, shared K/V frags)
  flash_attn<<<dim3(BB * NHEAD * 16), dim3(256), 0, stream>>>(QKV, VT, OB);
  // 9: out-proj + residual(XD) -> AO (= y)
  gemm_lds64<0, 2><<<dim3(64, 8), dim3(256), 0, stream>>>(OB, WOW, obs, XD,
                                                          AO, BB * SS, DDIM, DDIM);
  // 10: rmsnorm2 (AO -> NORM)
  rmsnorm_k<<<dim3(BB * SS), dim3(256), 0, stream>>>(AO, ln2, NORM);
  // 11: ffn1 + gelu -> HB   [4096 x 4096]  (HB aliases dead QKV/VT)
  gemm_lds<1, 1><<<dim3(32, 32), dim3(256), 0, stream>>>(NORM, W1B, b1, nullptr,
                                                         HB, BB * SS, 4 * DDIM, DDIM);
  // 12: ffn2 split-K=2, ONE launch (512 co-resident blocks) -> PK0/PK1
  gemm_part2<<<dim3(32, 8, 2), dim3(256), 0, stream>>>(HB, W2B, PK0, PK1,
                                                       BB * SS, DDIM, 2 * DDIM, 4 * DDIM);
  // 13: final out = y + PK0 + PK1 + b2 + mhc(XD)  (ffn2 epilogue fused here)
  final_k<<<dim3(BB * SS), dim3(256), 0, stream>>>(AO, PK0, PK1, b2, XD,
                                                   HRES, GRES, out);
}